// Round 1
// baseline (5533.656 us; speedup 1.0000x reference)
//
#include <hip/hip_runtime.h>
#include <math.h>

#define N_PIX 4096  // H*W = 64*64
#define BATCH 4

// ---------------------------------------------------------------------------
// Block-wide sum reduction (256 threads)
// ---------------------------------------------------------------------------
__device__ __forceinline__ float block_reduce_sum(float v, float* red) {
    int t = threadIdx.x;
    red[t] = v;
    __syncthreads();
    for (int s = 128; s > 0; s >>= 1) {
        if (t < s) red[t] += red[t + s];
        __syncthreads();
    }
    float r = red[0];
    __syncthreads();
    return r;
}

// ---------------------------------------------------------------------------
// Spectral norm: one power-iteration step -> 1/sigma written to out_inv.
// v = l2n(W^T u); s = W v; sigma = ||s||^2 / (||s|| + 1e-12)
// One block of 256 threads per layer (tiny work: O,C <= 512).
// ---------------------------------------------------------------------------
__global__ __launch_bounds__(256)
void sigma_kernel(const float* __restrict__ W, const float* __restrict__ u,
                  int O, int C, float* __restrict__ out_inv) {
    __shared__ float red[256];
    __shared__ float vsh[512];
    int t = threadIdx.x;
    float part = 0.f;
    for (int c = t; c < C; c += 256) {
        float acc = 0.f;
        for (int o = 0; o < O; ++o) acc += W[o * C + c] * u[o];
        vsh[c] = acc;
        part += acc * acc;
    }
    float nrm2 = block_reduce_sum(part, red);
    float rinv = 1.f / (sqrtf(nrm2) + 1e-12f);
    for (int c = t; c < C; c += 256) vsh[c] *= rinv;
    __syncthreads();
    float part2 = 0.f;
    for (int o = t; o < O; o += 256) {
        float acc = 0.f;
        for (int c = 0; c < C; ++c) acc += W[o * C + c] * vsh[c];
        part2 += acc * acc;
    }
    float ns2 = block_reduce_sum(part2, red);
    if (t == 0) {
        float sig = ns2 / (sqrtf(ns2) + 1e-12f);
        out_inv[0] = 1.f / sig;
    }
}

// ---------------------------------------------------------------------------
// 1x1 conv as GEMM: out[b,o,n] = act(inv_sigma * sum_c W[o,c]*x[b,c,n] + bias[o])
// Tile: 64(o) x 64(n), K-chunk 16. Block 256 threads, each computes 4x4.
// Fully bounds-checked in O and C (handles O=1, C=6).
// ---------------------------------------------------------------------------
__global__ __launch_bounds__(256)
void conv1x1_kernel(const float* __restrict__ x, const float* __restrict__ W,
                    const float* __restrict__ bias, const float* __restrict__ sig,
                    float* __restrict__ out, int C, int O, int lrelu) {
    __shared__ float Ws[16][68];  // [c][o], pad to 68 for bank spread + 16B align
    __shared__ float Xs[16][68];  // [c][n]
    int t = threadIdx.x;
    int tx = t & 15, ty = t >> 4;
    int b = blockIdx.z;
    int n0 = blockIdx.x * 64, o0 = blockIdx.y * 64;
    float acc[4][4] = {};
    const float* xb = x + (size_t)b * C * N_PIX;
    for (int c0 = 0; c0 < C; c0 += 16) {
        #pragma unroll
        for (int i = 0; i < 4; ++i) {  // W tile: 64 o x 16 c
            int e = t + i * 256;
            int o = e >> 4, c = e & 15;
            float wv = 0.f;
            if (o0 + o < O && c0 + c < C) wv = W[(size_t)(o0 + o) * C + c0 + c];
            Ws[c][o] = wv;
        }
        #pragma unroll
        for (int i = 0; i < 4; ++i) {  // X tile: 16 c x 64 n
            int e = t + i * 256;
            int c = e >> 6, n = e & 63;
            float xv = 0.f;
            if (c0 + c < C) xv = xb[(size_t)(c0 + c) * N_PIX + n0 + n];
            Xs[c][n] = xv;
        }
        __syncthreads();
        #pragma unroll
        for (int cc = 0; cc < 16; ++cc) {
            float4 wv = *(const float4*)&Ws[cc][ty * 4];
            float4 xv = *(const float4*)&Xs[cc][tx * 4];
            float wa[4] = {wv.x, wv.y, wv.z, wv.w};
            float xa[4] = {xv.x, xv.y, xv.z, xv.w};
            #pragma unroll
            for (int i = 0; i < 4; ++i)
                #pragma unroll
                for (int j = 0; j < 4; ++j)
                    acc[i][j] += wa[i] * xa[j];
        }
        __syncthreads();
    }
    float iv = sig ? sig[0] : 1.f;
    for (int i = 0; i < 4; ++i) {
        int o = o0 + ty * 4 + i;
        if (o >= O) break;  // no syncs below — safe
        float bv = bias[o];
        float vres[4];
        #pragma unroll
        for (int j = 0; j < 4; ++j) {
            float v = acc[i][j] * iv + bv;
            if (lrelu) v = (v > 0.f) ? v : 0.1f * v;
            vres[j] = v;
        }
        *(float4*)&out[((size_t)b * O + o) * N_PIX + n0 + tx * 4] =
            make_float4(vres[0], vres[1], vres[2], vres[3]);
    }
}

// ---------------------------------------------------------------------------
// Attention pass A: per-query online softmax stats over a key split.
// grid (N/256, B, 16 splits), block 256 (1 query/thread, 256 keys/split).
// ---------------------------------------------------------------------------
template <int CQ>
__global__ __launch_bounds__(256)
void attn_pass_a(const float* __restrict__ q, const float* __restrict__ k,
                 float* __restrict__ pmx, float* __restrict__ pl) {
    __shared__ float ks[CQ * 64];
    int t = threadIdx.x;
    int b = blockIdx.y, kz = blockIdx.z;
    int m = blockIdx.x * 256 + t;
    float qreg[CQ];
    #pragma unroll
    for (int c = 0; c < CQ; ++c) qreg[c] = q[((size_t)b * CQ + c) * N_PIX + m];
    float mx = -1e30f, l = 0.f;
    for (int tt = 0; tt < 4; ++tt) {
        int n0 = kz * 256 + tt * 64;
        for (int e = t; e < CQ * 64; e += 256)
            ks[e] = k[((size_t)b * CQ + (e >> 6)) * N_PIX + n0 + (e & 63)];
        __syncthreads();
        for (int j = 0; j < 64; ++j) {
            float s = 0.f;
            #pragma unroll
            for (int c = 0; c < CQ; ++c) s += qreg[c] * ks[c * 64 + j];
            float nm = fmaxf(mx, s);
            l = l * __expf(mx - nm) + __expf(s - nm);
            mx = nm;
        }
        __syncthreads();
    }
    pmx[((size_t)b * 16 + kz) * N_PIX + m] = mx;
    pl[((size_t)b * 16 + kz) * N_PIX + m] = l;
}

// Combine 16 split stats -> final max + 1/sum per query.
__global__ __launch_bounds__(256)
void attn_combine(const float* __restrict__ pmx, const float* __restrict__ pl,
                  float* __restrict__ smx, float* __restrict__ sil) {
    int idx = blockIdx.x * 256 + threadIdx.x;  // over B*N
    int b = idx >> 12, m = idx & 4095;
    float gm = -1e30f;
    for (int z = 0; z < 16; ++z)
        gm = fmaxf(gm, pmx[((size_t)b * 16 + z) * N_PIX + m]);
    float gl = 0.f;
    for (int z = 0; z < 16; ++z)
        gl += pl[((size_t)b * 16 + z) * N_PIX + m] *
              __expf(pmx[((size_t)b * 16 + z) * N_PIX + m] - gm);
    smx[idx] = gm;
    sil[idx] = 1.f / gl;
}

// ---------------------------------------------------------------------------
// Attention pass B: out[b,c,m] = gamma * sum_n p[m,n]*v[b,c,n] + x[b,c,m]
// p[m,n] = exp(q_m.k_n - mx_m) * inv_l_m  (recomputed per 16-key tile).
// Block: 32 queries x all C channels; 256 threads; acc in registers.
// ---------------------------------------------------------------------------
template <int CQ, int CC>
__global__ __launch_bounds__(256)
void attn_pass_b(const float* __restrict__ q, const float* __restrict__ k,
                 const float* __restrict__ v, const float* __restrict__ xin,
                 const float* __restrict__ smx, const float* __restrict__ sil,
                 const float* __restrict__ gamma, float* __restrict__ out) {
    __shared__ float qs[CQ * 32];        // [c][m]
    __shared__ float ks[CQ * 16];        // [c][j]
    __shared__ float vt[16 * (CC + 1)];  // [j][c], pad stride
    __shared__ float p[32 * 17];         // [m][j], pad stride
    __shared__ float mxs[32], ils[32];
    int t = threadIdx.x;
    int b = blockIdx.y;
    int m0 = blockIdx.x * 32;
    for (int e = t; e < CQ * 32; e += 256)
        qs[e] = q[((size_t)b * CQ + (e >> 5)) * N_PIX + m0 + (e & 31)];
    if (t < 32) {
        mxs[t] = smx[b * N_PIX + m0 + t];
        ils[t] = sil[b * N_PIX + m0 + t];
    }
    __syncthreads();
    const int KK = CC / 32;
    float acc[4][CC / 32] = {};
    int tq = t & 7, tc = t >> 3;
    for (int n0 = 0; n0 < N_PIX; n0 += 16) {
        for (int e = t; e < CQ * 16; e += 256)
            ks[e] = k[((size_t)b * CQ + (e >> 4)) * N_PIX + n0 + (e & 15)];
        for (int e = t; e < CC * 16; e += 256) {
            int c = e >> 4, j = e & 15;
            vt[j * (CC + 1) + c] = v[((size_t)b * CC + c) * N_PIX + n0 + j];
        }
        __syncthreads();
        #pragma unroll
        for (int r = 0; r < 2; ++r) {
            int pi = t + 256 * r;
            int mm = pi & 31, j = pi >> 5;
            float s = 0.f;
            #pragma unroll
            for (int c = 0; c < CQ; ++c) s += qs[c * 32 + mm] * ks[c * 16 + j];
            p[mm * 17 + j] = __expf(s - mxs[mm]) * ils[mm];
        }
        __syncthreads();
        #pragma unroll
        for (int j = 0; j < 16; ++j) {
            float pv[4];
            #pragma unroll
            for (int i = 0; i < 4; ++i) pv[i] = p[(tq + 8 * i) * 17 + j];
            #pragma unroll
            for (int kk = 0; kk < KK; ++kk) {
                float vv = vt[j * (CC + 1) + tc + 32 * kk];
                #pragma unroll
                for (int i = 0; i < 4; ++i) acc[i][kk] += pv[i] * vv;
            }
        }
        __syncthreads();
    }
    float g = gamma[0];
    for (int kk = 0; kk < KK; ++kk) {
        int c = tc + 32 * kk;
        for (int i = 0; i < 4; ++i) {
            int m = m0 + tq + 8 * i;
            size_t idx = ((size_t)b * CC + c) * N_PIX + m;
            out[idx] = g * acc[i][kk] + xin[idx];
        }
    }
}

// ---------------------------------------------------------------------------
// Launcher
// ---------------------------------------------------------------------------
extern "C" void kernel_launch(void* const* d_in, const int* in_sizes, int n_in,
                              void* d_out, int out_size, void* d_ws, size_t ws_size,
                              hipStream_t stream) {
    const float* x   = (const float*)d_in[0];
    const float* W1  = (const float*)d_in[1];
    const float* b1  = (const float*)d_in[2];
    const float* u1  = (const float*)d_in[3];
    const float* W2  = (const float*)d_in[4];
    const float* b2  = (const float*)d_in[5];
    const float* u2  = (const float*)d_in[6];
    const float* W3  = (const float*)d_in[7];
    const float* b3  = (const float*)d_in[8];
    const float* u3  = (const float*)d_in[9];
    const float* W4  = (const float*)d_in[10];
    const float* b4  = (const float*)d_in[11];
    const float* u4  = (const float*)d_in[12];
    const float* W5  = (const float*)d_in[13];
    const float* b5  = (const float*)d_in[14];
    const float* u5  = (const float*)d_in[15];
    const float* a1_qW = (const float*)d_in[16];
    const float* a1_qb = (const float*)d_in[17];
    const float* a1_kW = (const float*)d_in[18];
    const float* a1_kb = (const float*)d_in[19];
    const float* a1_vW = (const float*)d_in[20];
    const float* a1_vb = (const float*)d_in[21];
    const float* a1_g  = (const float*)d_in[22];
    const float* a2_qW = (const float*)d_in[23];
    const float* a2_qb = (const float*)d_in[24];
    const float* a2_kW = (const float*)d_in[25];
    const float* a2_kb = (const float*)d_in[26];
    const float* a2_vW = (const float*)d_in[27];
    const float* a2_vb = (const float*)d_in[28];
    const float* a2_g  = (const float*)d_in[29];

    float* ws = (float*)d_ws;
    // workspace layout (floats); total ~27.8M floats (~111 MB)
    float* sig  = ws;                       // 16
    float* pmx  = ws + 16;                  // B*16*N = 262144
    float* pl   = pmx + BATCH * 16 * N_PIX; // 262144
    float* smx  = pl + BATCH * 16 * N_PIX;  // 16384
    float* sil  = smx + BATCH * N_PIX;      // 16384
    float* bufA = sil + BATCH * N_PIX;      // 8M floats
    float* bufB = bufA + (size_t)BATCH * 512 * N_PIX;
    float* qb   = bufB + (size_t)BATCH * 512 * N_PIX;  // 1M
    float* kb   = qb + (size_t)BATCH * 64 * N_PIX;     // 1M
    float* vb   = kb + (size_t)BATCH * 64 * N_PIX;     // 8M

    dim3 blk(256);

    // spectral norms
    sigma_kernel<<<1, blk, 0, stream>>>(W1, u1, 64, 6, sig + 0);
    sigma_kernel<<<1, blk, 0, stream>>>(W2, u2, 128, 64, sig + 1);
    sigma_kernel<<<1, blk, 0, stream>>>(W3, u3, 256, 128, sig + 2);
    sigma_kernel<<<1, blk, 0, stream>>>(W4, u4, 512, 256, sig + 3);
    sigma_kernel<<<1, blk, 0, stream>>>(W5, u5, 1, 512, sig + 4);

    // L1: (4,6,N) -> (4,64,N)
    conv1x1_kernel<<<dim3(64, 1, 4), blk, 0, stream>>>(x, W1, b1, sig + 0, bufA, 6, 64, 1);
    // L2: -> (4,128,N)
    conv1x1_kernel<<<dim3(64, 2, 4), blk, 0, stream>>>(bufA, W2, b2, sig + 1, bufB, 64, 128, 1);
    // L3: -> (4,256,N)
    conv1x1_kernel<<<dim3(64, 4, 4), blk, 0, stream>>>(bufB, W3, b3, sig + 2, bufA, 128, 256, 1);

    // attention 1 (C=256, Cq=32), input bufA -> bufB
    conv1x1_kernel<<<dim3(64, 1, 4), blk, 0, stream>>>(bufA, a1_qW, a1_qb, nullptr, qb, 256, 32, 0);
    conv1x1_kernel<<<dim3(64, 1, 4), blk, 0, stream>>>(bufA, a1_kW, a1_kb, nullptr, kb, 256, 32, 0);
    conv1x1_kernel<<<dim3(64, 4, 4), blk, 0, stream>>>(bufA, a1_vW, a1_vb, nullptr, vb, 256, 256, 0);
    attn_pass_a<32><<<dim3(16, 4, 16), blk, 0, stream>>>(qb, kb, pmx, pl);
    attn_combine<<<dim3(64), blk, 0, stream>>>(pmx, pl, smx, sil);
    attn_pass_b<32, 256><<<dim3(128, 4), blk, 0, stream>>>(qb, kb, vb, bufA, smx, sil, a1_g, bufB);

    // L4: -> (4,512,N), bufB -> bufA
    conv1x1_kernel<<<dim3(64, 8, 4), blk, 0, stream>>>(bufB, W4, b4, sig + 3, bufA, 256, 512, 1);

    // attention 2 (C=512, Cq=64), input bufA -> bufB
    conv1x1_kernel<<<dim3(64, 1, 4), blk, 0, stream>>>(bufA, a2_qW, a2_qb, nullptr, qb, 512, 64, 0);
    conv1x1_kernel<<<dim3(64, 1, 4), blk, 0, stream>>>(bufA, a2_kW, a2_kb, nullptr, kb, 512, 64, 0);
    conv1x1_kernel<<<dim3(64, 8, 4), blk, 0, stream>>>(bufA, a2_vW, a2_vb, nullptr, vb, 512, 512, 0);
    attn_pass_a<64><<<dim3(16, 4, 16), blk, 0, stream>>>(qb, kb, pmx, pl);
    attn_combine<<<dim3(64), blk, 0, stream>>>(pmx, pl, smx, sil);
    attn_pass_b<64, 512><<<dim3(128, 4), blk, 0, stream>>>(qb, kb, vb, bufA, smx, sil, a2_g, bufB);

    // L5: -> (4,1,N) == d_out (B,H,W)
    conv1x1_kernel<<<dim3(64, 1, 4), blk, 0, stream>>>(bufB, W5, b5, sig + 4, (float*)d_out, 512, 1, 1);
}

// Round 2
// 1625.998 us; speedup vs baseline: 3.4032x; 3.4032x over previous
//
#include <hip/hip_runtime.h>
#include <math.h>

#define N_PIX 4096  // H*W = 64*64
#define BATCH 4

typedef __bf16 bf16x8 __attribute__((ext_vector_type(8)));
typedef __bf16 bf16x4v __attribute__((ext_vector_type(4)));
typedef float f32x4 __attribute__((ext_vector_type(4)));

// ---------------------------------------------------------------------------
// Block-wide sum reduction (256 threads)
// ---------------------------------------------------------------------------
__device__ __forceinline__ float block_reduce_sum(float v, float* red) {
    int t = threadIdx.x;
    red[t] = v;
    __syncthreads();
    for (int s = 128; s > 0; s >>= 1) {
        if (t < s) red[t] += red[t + s];
        __syncthreads();
    }
    float r = red[0];
    __syncthreads();
    return r;
}

// ---------------------------------------------------------------------------
// Spectral norm: one power-iteration -> 1/sigma.
// ---------------------------------------------------------------------------
__global__ __launch_bounds__(256)
void sigma_kernel(const float* __restrict__ W, const float* __restrict__ u,
                  int O, int C, float* __restrict__ out_inv) {
    __shared__ float red[256];
    __shared__ float vsh[512];
    int t = threadIdx.x;
    float part = 0.f;
    for (int c = t; c < C; c += 256) {
        float acc = 0.f;
        for (int o = 0; o < O; ++o) acc += W[o * C + c] * u[o];
        vsh[c] = acc;
        part += acc * acc;
    }
    float nrm2 = block_reduce_sum(part, red);
    float rinv = 1.f / (sqrtf(nrm2) + 1e-12f);
    for (int c = t; c < C; c += 256) vsh[c] *= rinv;
    __syncthreads();
    float part2 = 0.f;
    for (int o = t; o < O; o += 256) {
        float acc = 0.f;
        for (int c = 0; c < C; ++c) acc += W[o * C + c] * vsh[c];
        part2 += acc * acc;
    }
    float ns2 = block_reduce_sum(part2, red);
    if (t == 0) {
        float sig = ns2 / (sqrtf(ns2) + 1e-12f);
        out_inv[0] = 1.f / sig;
    }
}

// ---------------------------------------------------------------------------
// 1x1 conv as GEMM (fp32 math). OUT_BF16=1 stores bf16, else fp32.
// ---------------------------------------------------------------------------
template <int OUT_BF16>
__global__ __launch_bounds__(256)
void conv1x1_kernel(const float* __restrict__ x, const float* __restrict__ W,
                    const float* __restrict__ bias, const float* __restrict__ sig,
                    void* __restrict__ outp, int C, int O, int lrelu) {
    __shared__ float Ws[16][68];
    __shared__ float Xs[16][68];
    int t = threadIdx.x;
    int tx = t & 15, ty = t >> 4;
    int b = blockIdx.z;
    int n0 = blockIdx.x * 64, o0 = blockIdx.y * 64;
    float acc[4][4] = {};
    const float* xb = x + (size_t)b * C * N_PIX;
    for (int c0 = 0; c0 < C; c0 += 16) {
        #pragma unroll
        for (int i = 0; i < 4; ++i) {
            int e = t + i * 256;
            int o = e >> 4, c = e & 15;
            float wv = 0.f;
            if (o0 + o < O && c0 + c < C) wv = W[(size_t)(o0 + o) * C + c0 + c];
            Ws[c][o] = wv;
        }
        #pragma unroll
        for (int i = 0; i < 4; ++i) {
            int e = t + i * 256;
            int c = e >> 6, n = e & 63;
            float xv = 0.f;
            if (c0 + c < C) xv = xb[(size_t)(c0 + c) * N_PIX + n0 + n];
            Xs[c][n] = xv;
        }
        __syncthreads();
        #pragma unroll
        for (int cc = 0; cc < 16; ++cc) {
            float4 wv = *(const float4*)&Ws[cc][ty * 4];
            float4 xv = *(const float4*)&Xs[cc][tx * 4];
            float wa[4] = {wv.x, wv.y, wv.z, wv.w};
            float xa[4] = {xv.x, xv.y, xv.z, xv.w};
            #pragma unroll
            for (int i = 0; i < 4; ++i)
                #pragma unroll
                for (int j = 0; j < 4; ++j)
                    acc[i][j] += wa[i] * xa[j];
        }
        __syncthreads();
    }
    float iv = sig ? sig[0] : 1.f;
    for (int i = 0; i < 4; ++i) {
        int o = o0 + ty * 4 + i;
        if (o >= O) break;
        float bv = bias[o];
        size_t idx = ((size_t)b * O + o) * N_PIX + n0 + tx * 4;
        if (OUT_BF16) {
            __bf16* out = (__bf16*)outp;
            bf16x4v v4;
            #pragma unroll
            for (int j = 0; j < 4; ++j) {
                float v = acc[i][j] * iv + bv;
                if (lrelu) v = (v > 0.f) ? v : 0.1f * v;
                v4[j] = (__bf16)v;
            }
            *(bf16x4v*)&out[idx] = v4;
        } else {
            float* out = (float*)outp;
            float vres[4];
            #pragma unroll
            for (int j = 0; j < 4; ++j) {
                float v = acc[i][j] * iv + bv;
                if (lrelu) v = (v > 0.f) ? v : 0.1f * v;
                vres[j] = v;
            }
            *(float4*)&out[idx] = make_float4(vres[0], vres[1], vres[2], vres[3]);
        }
    }
}

// ---------------------------------------------------------------------------
// Transpose (B, CQ, N) fp32 -> (B, N, CQ) bf16. Tiny; once per attention.
// ---------------------------------------------------------------------------
template <int CQ>
__global__ __launch_bounds__(256)
void transpose_to_bf16(const float* __restrict__ in, __bf16* __restrict__ out) {
    __shared__ float tile[64][65];
    int t = threadIdx.x;
    int n0 = blockIdx.x * 64, b = blockIdx.y;
    for (int e = t; e < CQ * 64; e += 256) {
        int c = e >> 6, j = e & 63;
        tile[j][c] = in[((size_t)b * CQ + c) * N_PIX + n0 + j];
    }
    __syncthreads();
    for (int e = t; e < 64 * CQ; e += 256) {
        int j = e / CQ, c = e % CQ;
        out[((size_t)b * N_PIX + n0 + j) * CQ + c] = (__bf16)tile[j][c];
    }
}

// ---------------------------------------------------------------------------
// Fused flash attention with bf16 MFMA.
// qt/kt: (B, N, CQ) bf16.  vg: (B, C, N) bf16.  xin/out: (B, C, N) fp32.
// Block: 64 queries x CCH channels, 4 waves (one 16-query row-tile per wave).
// Per 64-key tile: S = Q.K^T via MFMA -> online softmax -> P.V via MFMA.
// MFMA layouts (verified m89/m120): A[m=lane&15][k=quad*8+j],
// B[k=quad*8+j][n=lane&15], D[row=quad*4+reg][col=lane&15].
// ---------------------------------------------------------------------------
template <int CQ, int CCH>
__global__ __launch_bounds__(256)
void attn_fused(const __bf16* __restrict__ qt, const __bf16* __restrict__ kt,
                const __bf16* __restrict__ vg, const float* __restrict__ xin,
                const float* __restrict__ gamma, float* __restrict__ out, int C) {
    constexpr int CQP = CQ + 8;   // pad keeps 16B alignment, 2-way banks (free)
    __shared__ __bf16 qs[64 * CQP];   // [query][c]
    __shared__ __bf16 ks[64 * CQP];   // [key][c]
    __shared__ __bf16 vs[CCH * 72];   // [c][key]
    __shared__ __bf16 ps[64 * 72];    // [query][key]
    int t = threadIdx.x;
    int lane = t & 63, w = t >> 6;
    int l15 = lane & 15, quad = lane >> 4;
    int b = blockIdx.z, c0 = blockIdx.y * CCH, m0 = blockIdx.x * 64;

    // stage Q once
    constexpr int CG = CQ / 8;
    for (int ch = t; ch < 64 * CG; ch += 256) {
        int m = ch / CG, cg = ch % CG;
        *(uint4*)&qs[m * CQP + cg * 8] =
            *(const uint4*)&qt[((size_t)b * N_PIX + m0 + m) * CQ + cg * 8];
    }

    f32x4 acc[CCH / 16] = {};
    float run_m[4], run_l[4];
    #pragma unroll
    for (int r = 0; r < 4; ++r) { run_m[r] = -1e30f; run_l[r] = 0.f; }

    for (int n0 = 0; n0 < N_PIX; n0 += 64) {
        __syncthreads();  // protect ks/vs against previous tile's readers
        for (int ch = t; ch < 64 * CG; ch += 256) {
            int j = ch / CG, cg = ch % CG;
            *(uint4*)&ks[j * CQP + cg * 8] =
                *(const uint4*)&kt[((size_t)b * N_PIX + n0 + j) * CQ + cg * 8];
        }
        for (int ch = t; ch < CCH * 8; ch += 256) {
            int c = ch >> 3, jg = ch & 7;
            *(uint4*)&vs[c * 72 + jg * 8] =
                *(const uint4*)&vg[((size_t)b * C + c0 + c) * N_PIX + n0 + jg * 8];
        }
        __syncthreads();

        // S tile: 16 queries (this wave) x 64 keys
        f32x4 s[4] = {};
        #pragma unroll
        for (int kk = 0; kk < CQ / 32; ++kk) {
            bf16x8 af = *(const bf16x8*)&qs[(w * 16 + l15) * CQP + kk * 32 + quad * 8];
            #pragma unroll
            for (int kt4 = 0; kt4 < 4; ++kt4) {
                bf16x8 bfr = *(const bf16x8*)&ks[(kt4 * 16 + l15) * CQP + kk * 32 + quad * 8];
                s[kt4] = __builtin_amdgcn_mfma_f32_16x16x32_bf16(af, bfr, s[kt4], 0, 0, 0);
            }
        }

        // online softmax; row r = query quad*4+r of this wave's row-tile
        #pragma unroll
        for (int r = 0; r < 4; ++r) {
            float rm = fmaxf(fmaxf(s[0][r], s[1][r]), fmaxf(s[2][r], s[3][r]));
            #pragma unroll
            for (int off = 1; off < 16; off <<= 1) rm = fmaxf(rm, __shfl_xor(rm, off));
            float nm = fmaxf(run_m[r], rm);
            float alpha = __expf(run_m[r] - nm);
            float psum = 0.f;
            #pragma unroll
            for (int kt4 = 0; kt4 < 4; ++kt4) {
                float p = __expf(s[kt4][r] - nm);
                s[kt4][r] = p;
                psum += p;
            }
            #pragma unroll
            for (int off = 1; off < 16; off <<= 1) psum += __shfl_xor(psum, off);
            run_l[r] = run_l[r] * alpha + psum;
            run_m[r] = nm;
            #pragma unroll
            for (int i = 0; i < CCH / 16; ++i) acc[i][r] *= alpha;
        }

        // P -> LDS (bf16). Same-wave rows only; DS in-order, no barrier needed.
        #pragma unroll
        for (int kt4 = 0; kt4 < 4; ++kt4)
            #pragma unroll
            for (int r = 0; r < 4; ++r)
                ps[(w * 16 + quad * 4 + r) * 72 + kt4 * 16 + l15] = (__bf16)s[kt4][r];

        // PV: acc[m][c] += P[m][key] * V[key][c]
        #pragma unroll
        for (int kk2 = 0; kk2 < 2; ++kk2) {
            bf16x8 af = *(const bf16x8*)&ps[(w * 16 + l15) * 72 + kk2 * 32 + quad * 8];
            #pragma unroll
            for (int ct = 0; ct < CCH / 16; ++ct) {
                bf16x8 bfr = *(const bf16x8*)&vs[(ct * 16 + l15) * 72 + kk2 * 32 + quad * 8];
                acc[ct] = __builtin_amdgcn_mfma_f32_16x16x32_bf16(af, bfr, acc[ct], 0, 0, 0);
            }
        }
    }

    float g = gamma[0];
    #pragma unroll
    for (int r = 0; r < 4; ++r) {
        float il = 1.f / run_l[r];
        int m = m0 + w * 16 + quad * 4 + r;
        #pragma unroll
        for (int ct = 0; ct < CCH / 16; ++ct) {
            int c = c0 + ct * 16 + l15;
            size_t idx = ((size_t)b * C + c) * N_PIX + m;
            out[idx] = g * acc[ct][r] * il + xin[idx];
        }
    }
}

// ---------------------------------------------------------------------------
// Launcher
// ---------------------------------------------------------------------------
extern "C" void kernel_launch(void* const* d_in, const int* in_sizes, int n_in,
                              void* d_out, int out_size, void* d_ws, size_t ws_size,
                              hipStream_t stream) {
    const float* x   = (const float*)d_in[0];
    const float* W1  = (const float*)d_in[1];
    const float* b1  = (const float*)d_in[2];
    const float* u1  = (const float*)d_in[3];
    const float* W2  = (const float*)d_in[4];
    const float* b2  = (const float*)d_in[5];
    const float* u2  = (const float*)d_in[6];
    const float* W3  = (const float*)d_in[7];
    const float* b3  = (const float*)d_in[8];
    const float* u3  = (const float*)d_in[9];
    const float* W4  = (const float*)d_in[10];
    const float* b4  = (const float*)d_in[11];
    const float* u4  = (const float*)d_in[12];
    const float* W5  = (const float*)d_in[13];
    const float* b5  = (const float*)d_in[14];
    const float* u5  = (const float*)d_in[15];
    const float* a1_qW = (const float*)d_in[16];
    const float* a1_qb = (const float*)d_in[17];
    const float* a1_kW = (const float*)d_in[18];
    const float* a1_kb = (const float*)d_in[19];
    const float* a1_vW = (const float*)d_in[20];
    const float* a1_vb = (const float*)d_in[21];
    const float* a1_g  = (const float*)d_in[22];
    const float* a2_qW = (const float*)d_in[23];
    const float* a2_qb = (const float*)d_in[24];
    const float* a2_kW = (const float*)d_in[25];
    const float* a2_kb = (const float*)d_in[26];
    const float* a2_vW = (const float*)d_in[27];
    const float* a2_vb = (const float*)d_in[28];
    const float* a2_g  = (const float*)d_in[29];

    float* ws = (float*)d_ws;
    const size_t SZ_ACT = (size_t)BATCH * 512 * N_PIX;  // 8M floats
    float* sig  = ws;                        // 16
    float* bufA = ws + 16;
    float* bufB = bufA + SZ_ACT;
    float* qf   = bufB + SZ_ACT;                         // 1M fp32
    float* kf   = qf + (size_t)BATCH * 64 * N_PIX;       // 1M fp32
    __bf16* qt  = (__bf16*)(kf + (size_t)BATCH * 64 * N_PIX);  // 1M bf16
    __bf16* ktb = qt + (size_t)BATCH * N_PIX * 64;             // 1M bf16
    __bf16* vb  = ktb + (size_t)BATCH * N_PIX * 64;            // 8M bf16

    dim3 blk(256);

    sigma_kernel<<<1, blk, 0, stream>>>(W1, u1, 64, 6, sig + 0);
    sigma_kernel<<<1, blk, 0, stream>>>(W2, u2, 128, 64, sig + 1);
    sigma_kernel<<<1, blk, 0, stream>>>(W3, u3, 256, 128, sig + 2);
    sigma_kernel<<<1, blk, 0, stream>>>(W4, u4, 512, 256, sig + 3);
    sigma_kernel<<<1, blk, 0, stream>>>(W5, u5, 1, 512, sig + 4);

    conv1x1_kernel<0><<<dim3(64, 1, 4), blk, 0, stream>>>(x, W1, b1, sig + 0, bufA, 6, 64, 1);
    conv1x1_kernel<0><<<dim3(64, 2, 4), blk, 0, stream>>>(bufA, W2, b2, sig + 1, bufB, 64, 128, 1);
    conv1x1_kernel<0><<<dim3(64, 4, 4), blk, 0, stream>>>(bufB, W3, b3, sig + 2, bufA, 128, 256, 1);

    // attention 1 (C=256, Cq=32): bufA -> bufB
    conv1x1_kernel<0><<<dim3(64, 1, 4), blk, 0, stream>>>(bufA, a1_qW, a1_qb, nullptr, qf, 256, 32, 0);
    conv1x1_kernel<0><<<dim3(64, 1, 4), blk, 0, stream>>>(bufA, a1_kW, a1_kb, nullptr, kf, 256, 32, 0);
    conv1x1_kernel<1><<<dim3(64, 4, 4), blk, 0, stream>>>(bufA, a1_vW, a1_vb, nullptr, vb, 256, 256, 0);
    transpose_to_bf16<32><<<dim3(64, 4), blk, 0, stream>>>(qf, qt);
    transpose_to_bf16<32><<<dim3(64, 4), blk, 0, stream>>>(kf, ktb);
    attn_fused<32, 128><<<dim3(64, 2, 4), blk, 0, stream>>>(qt, ktb, vb, bufA, a1_g, bufB, 256);

    conv1x1_kernel<0><<<dim3(64, 8, 4), blk, 0, stream>>>(bufB, W4, b4, sig + 3, bufA, 256, 512, 1);

    // attention 2 (C=512, Cq=64): bufA -> bufB
    conv1x1_kernel<0><<<dim3(64, 1, 4), blk, 0, stream>>>(bufA, a2_qW, a2_qb, nullptr, qf, 512, 64, 0);
    conv1x1_kernel<0><<<dim3(64, 1, 4), blk, 0, stream>>>(bufA, a2_kW, a2_kb, nullptr, kf, 512, 64, 0);
    conv1x1_kernel<1><<<dim3(64, 8, 4), blk, 0, stream>>>(bufA, a2_vW, a2_vb, nullptr, vb, 512, 512, 0);
    transpose_to_bf16<64><<<dim3(64, 4), blk, 0, stream>>>(qf, qt);
    transpose_to_bf16<64><<<dim3(64, 4), blk, 0, stream>>>(kf, ktb);
    attn_fused<64, 128><<<dim3(64, 4, 4), blk, 0, stream>>>(qt, ktb, vb, bufA, a2_g, bufB, 512);

    conv1x1_kernel<0><<<dim3(64, 1, 4), blk, 0, stream>>>(bufB, W5, b5, sig + 4, d_out, 512, 1, 1);
}

// Round 3
// 1525.699 us; speedup vs baseline: 3.6270x; 1.0657x over previous
//
#include <hip/hip_runtime.h>
#include <math.h>

#define N_PIX 4096  // H*W = 64*64
#define BATCH 4
#define LOG2E 1.4426950408889634f

typedef __bf16 bf16x8 __attribute__((ext_vector_type(8)));
typedef __bf16 bf16x4v __attribute__((ext_vector_type(4)));
typedef float f32x4 __attribute__((ext_vector_type(4)));

// ---------------------------------------------------------------------------
// Block-wide sum reduction (256 threads)
// ---------------------------------------------------------------------------
__device__ __forceinline__ float block_reduce_sum(float v, float* red) {
    int t = threadIdx.x;
    red[t] = v;
    __syncthreads();
    for (int s = 128; s > 0; s >>= 1) {
        if (t < s) red[t] += red[t + s];
        __syncthreads();
    }
    float r = red[0];
    __syncthreads();
    return r;
}

// ---------------------------------------------------------------------------
// Spectral norm: one power-iteration -> 1/sigma.
// ---------------------------------------------------------------------------
__global__ __launch_bounds__(256)
void sigma_kernel(const float* __restrict__ W, const float* __restrict__ u,
                  int O, int C, float* __restrict__ out_inv) {
    __shared__ float red[256];
    __shared__ float vsh[512];
    int t = threadIdx.x;
    float part = 0.f;
    for (int c = t; c < C; c += 256) {
        float acc = 0.f;
        for (int o = 0; o < O; ++o) acc += W[o * C + c] * u[o];
        vsh[c] = acc;
        part += acc * acc;
    }
    float nrm2 = block_reduce_sum(part, red);
    float rinv = 1.f / (sqrtf(nrm2) + 1e-12f);
    for (int c = t; c < C; c += 256) vsh[c] *= rinv;
    __syncthreads();
    float part2 = 0.f;
    for (int o = t; o < O; o += 256) {
        float acc = 0.f;
        for (int c = 0; c < C; ++c) acc += W[o * C + c] * vsh[c];
        part2 += acc * acc;
    }
    float ns2 = block_reduce_sum(part2, red);
    if (t == 0) {
        float sig = ns2 / (sqrtf(ns2) + 1e-12f);
        out_inv[0] = 1.f / sig;
    }
}

// ---------------------------------------------------------------------------
// 1x1 conv as GEMM (fp32 math), input (B,C,N). OUT_BF16=1 stores bf16.
// ---------------------------------------------------------------------------
template <int OUT_BF16>
__global__ __launch_bounds__(256)
void conv1x1_kernel(const float* __restrict__ x, const float* __restrict__ W,
                    const float* __restrict__ bias, const float* __restrict__ sig,
                    void* __restrict__ outp, int C, int O, int lrelu) {
    __shared__ float Ws[16][68];
    __shared__ float Xs[16][68];
    int t = threadIdx.x;
    int tx = t & 15, ty = t >> 4;
    int b = blockIdx.z;
    int n0 = blockIdx.x * 64, o0 = blockIdx.y * 64;
    float acc[4][4] = {};
    const float* xb = x + (size_t)b * C * N_PIX;
    for (int c0 = 0; c0 < C; c0 += 16) {
        #pragma unroll
        for (int i = 0; i < 4; ++i) {
            int e = t + i * 256;
            int o = e >> 4, c = e & 15;
            float wv = 0.f;
            if (o0 + o < O && c0 + c < C) wv = W[(size_t)(o0 + o) * C + c0 + c];
            Ws[c][o] = wv;
        }
        #pragma unroll
        for (int i = 0; i < 4; ++i) {
            int e = t + i * 256;
            int c = e >> 6, n = e & 63;
            float xv = 0.f;
            if (c0 + c < C) xv = xb[(size_t)(c0 + c) * N_PIX + n0 + n];
            Xs[c][n] = xv;
        }
        __syncthreads();
        #pragma unroll
        for (int cc = 0; cc < 16; ++cc) {
            float4 wv = *(const float4*)&Ws[cc][ty * 4];
            float4 xv = *(const float4*)&Xs[cc][tx * 4];
            float wa[4] = {wv.x, wv.y, wv.z, wv.w};
            float xa[4] = {xv.x, xv.y, xv.z, xv.w};
            #pragma unroll
            for (int i = 0; i < 4; ++i)
                #pragma unroll
                for (int j = 0; j < 4; ++j)
                    acc[i][j] += wa[i] * xa[j];
        }
        __syncthreads();
    }
    float iv = sig ? sig[0] : 1.f;
    for (int i = 0; i < 4; ++i) {
        int o = o0 + ty * 4 + i;
        if (o >= O) break;
        float bv = bias[o];
        size_t idx = ((size_t)b * O + o) * N_PIX + n0 + tx * 4;
        if (OUT_BF16) {
            __bf16* out = (__bf16*)outp;
            bf16x4v v4;
            #pragma unroll
            for (int j = 0; j < 4; ++j) {
                float v = acc[i][j] * iv + bv;
                if (lrelu) v = (v > 0.f) ? v : 0.1f * v;
                v4[j] = (__bf16)v;
            }
            *(bf16x4v*)&out[idx] = v4;
        } else {
            float* out = (float*)outp;
            float vres[4];
            #pragma unroll
            for (int j = 0; j < 4; ++j) {
                float v = acc[i][j] * iv + bv;
                if (lrelu) v = (v > 0.f) ? v : 0.1f * v;
                vres[j] = v;
            }
            *(float4*)&out[idx] = make_float4(vres[0], vres[1], vres[2], vres[3]);
        }
    }
}

// ---------------------------------------------------------------------------
// 1x1 conv, TRANSPOSED input (B,N,C) fp32 -> output (B,O,N) fp32.
// ---------------------------------------------------------------------------
__global__ __launch_bounds__(256)
void conv1x1_t_kernel(const float* __restrict__ xt, const float* __restrict__ W,
                      const float* __restrict__ bias, const float* __restrict__ sig,
                      float* __restrict__ out, int C, int O, int lrelu) {
    __shared__ float Ws[16][68];
    __shared__ float Xs[16][68];
    int t = threadIdx.x;
    int tx = t & 15, ty = t >> 4;
    int b = blockIdx.z;
    int n0 = blockIdx.x * 64, o0 = blockIdx.y * 64;
    float acc[4][4] = {};
    const float* xb = xt + (size_t)b * N_PIX * C;
    for (int c0 = 0; c0 < C; c0 += 16) {
        #pragma unroll
        for (int i = 0; i < 4; ++i) {
            int e = t + i * 256;
            int o = e >> 4, c = e & 15;
            float wv = 0.f;
            if (o0 + o < O) wv = W[(size_t)(o0 + o) * C + c0 + c];
            Ws[c][o] = wv;
        }
        #pragma unroll
        for (int i = 0; i < 4; ++i) {
            int e = t + i * 256;
            int c = e & 15, n = e >> 4;  // consecutive threads -> consecutive c
            Xs[c][n] = xb[(size_t)(n0 + n) * C + c0 + c];
        }
        __syncthreads();
        #pragma unroll
        for (int cc = 0; cc < 16; ++cc) {
            float4 wv = *(const float4*)&Ws[cc][ty * 4];
            float4 xv = *(const float4*)&Xs[cc][tx * 4];
            float wa[4] = {wv.x, wv.y, wv.z, wv.w};
            float xa[4] = {xv.x, xv.y, xv.z, xv.w};
            #pragma unroll
            for (int i = 0; i < 4; ++i)
                #pragma unroll
                for (int j = 0; j < 4; ++j)
                    acc[i][j] += wa[i] * xa[j];
        }
        __syncthreads();
    }
    float iv = sig ? sig[0] : 1.f;
    for (int i = 0; i < 4; ++i) {
        int o = o0 + ty * 4 + i;
        if (o >= O) break;
        float bv = bias[o];
        float vres[4];
        #pragma unroll
        for (int j = 0; j < 4; ++j) {
            float v = acc[i][j] * iv + bv;
            if (lrelu) v = (v > 0.f) ? v : 0.1f * v;
            vres[j] = v;
        }
        *(float4*)&out[((size_t)b * O + o) * N_PIX + n0 + tx * 4] =
            make_float4(vres[0], vres[1], vres[2], vres[3]);
    }
}

// ---------------------------------------------------------------------------
// Transpose (B, CQ, N) fp32 -> (B, N, CQ) bf16, with scale (log2e for Q).
// ---------------------------------------------------------------------------
template <int CQ>
__global__ __launch_bounds__(256)
void transpose_to_bf16(const float* __restrict__ in, __bf16* __restrict__ out,
                       float scale) {
    __shared__ float tile[64][65];
    int t = threadIdx.x;
    int n0 = blockIdx.x * 64, b = blockIdx.y;
    for (int e = t; e < CQ * 64; e += 256) {
        int c = e >> 6, j = e & 63;
        tile[j][c] = in[((size_t)b * CQ + c) * N_PIX + n0 + j];
    }
    __syncthreads();
    for (int e = t; e < 64 * CQ; e += 256) {
        int j = e / CQ, c = e % CQ;
        out[((size_t)b * N_PIX + n0 + j) * CQ + c] = (__bf16)(tile[j][c] * scale);
    }
}

// ---------------------------------------------------------------------------
// Fused flash attention v2.
// qt/kt: (B,N,CQ) bf16 (qt pre-scaled by log2e). vg: (B,C,N) bf16.
// xin: (B,C,N) fp32 residual. out_t: (B,N,C) fp32 TRANSPOSED output.
// Block: 256 thr = 4 waves; wave handles 32 queries (2 m-frags); M=128/block.
// KT=128 keys/tile. Q in registers; K in LDS; V direct-from-global (L1/L2);
// P via LDS round-trip. exp2-domain softmax, deferred l, guarded rescale.
// MFMA frag maps (verified): A[m=l15][k=quad*8+j], B[k=quad*8+j][n=l15],
// D[row=quad*4+reg][col=l15].
// ---------------------------------------------------------------------------
template <int CQ, int CCH>
__global__ __launch_bounds__(256, 2)
void attn_fused2(const __bf16* __restrict__ qt, const __bf16* __restrict__ kt,
                 const __bf16* __restrict__ vg, const float* __restrict__ xin,
                 const float* __restrict__ gamma, float* __restrict__ out_t, int C) {
    constexpr int CQP = CQ + 8;
    constexpr int CG = CQ / 8;
    constexpr int KT = 128, KTI = 8, KK2 = 4;
    constexpr int NKK = CQ / 32;
    constexpr int CT = CCH / 16;
    __shared__ __bf16 ks[KT * CQP];
    __shared__ __bf16 ps[128 * 136];
    int t = threadIdx.x;
    int lane = t & 63, w = t >> 6;
    int l15 = lane & 15, quad = lane >> 4;
    int b = blockIdx.z, c0 = blockIdx.y * CCH, m0 = blockIdx.x * 128;

    // Q fragments in registers (row = query, k = channel)
    bf16x8 qf[2][NKK];
    #pragma unroll
    for (int m = 0; m < 2; ++m)
        #pragma unroll
        for (int kk = 0; kk < NKK; ++kk)
            qf[m][kk] = *(const bf16x8*)&qt[((size_t)b * N_PIX + m0 + w * 32 + m * 16 + l15) * CQ + kk * 32 + quad * 8];

    f32x4 acc[2][CT] = {};
    float run_m[2][4], lp[2][4];
    #pragma unroll
    for (int m = 0; m < 2; ++m)
        #pragma unroll
        for (int r = 0; r < 4; ++r) { run_m[m][r] = -1e30f; lp[m][r] = 0.f; }

    for (int n0 = 0; n0 < N_PIX; n0 += KT) {
        __syncthreads();  // protect ks against previous tile's readers
        for (int e = t; e < KT * CG; e += 256) {
            int row = e / CG, cg = e % CG;
            *(uint4*)&ks[row * CQP + cg * 8] =
                *(const uint4*)&kt[((size_t)b * N_PIX + n0 + row) * CQ + cg * 8];
        }
        __syncthreads();

        // S = Q.K^T : 2 m-frags x 128 keys
        f32x4 s[2][KTI] = {};
        #pragma unroll
        for (int kk = 0; kk < NKK; ++kk)
            #pragma unroll
            for (int kti = 0; kti < KTI; ++kti) {
                bf16x8 bfr = *(const bf16x8*)&ks[(kti * 16 + l15) * CQP + kk * 32 + quad * 8];
                #pragma unroll
                for (int m = 0; m < 2; ++m)
                    s[m][kti] = __builtin_amdgcn_mfma_f32_16x16x32_bf16(qf[m][kk], bfr, s[m][kti], 0, 0, 0);
            }

        // online softmax (exp2 domain), deferred l-reduction
        bool need = false;
        float alpha[2][4];
        #pragma unroll
        for (int m = 0; m < 2; ++m)
            #pragma unroll
            for (int r = 0; r < 4; ++r) {
                float tm = s[m][0][r];
                #pragma unroll
                for (int kti = 1; kti < KTI; ++kti) tm = fmaxf(tm, s[m][kti][r]);
                #pragma unroll
                for (int off = 1; off < 16; off <<= 1) tm = fmaxf(tm, __shfl_xor(tm, off));
                float nm = fmaxf(run_m[m][r], tm);
                float a = exp2f(run_m[m][r] - nm);
                alpha[m][r] = a;
                need = need || (a < 1.0f);
                run_m[m][r] = nm;
                float psum = 0.f;
                #pragma unroll
                for (int kti = 0; kti < KTI; ++kti) {
                    float p = exp2f(s[m][kti][r] - nm);
                    s[m][kti][r] = p;
                    psum += p;
                }
                lp[m][r] = lp[m][r] * a + psum;
            }
        if (__ballot(need)) {
            #pragma unroll
            for (int m = 0; m < 2; ++m)
                #pragma unroll
                for (int ct = 0; ct < CT; ++ct)
                    #pragma unroll
                    for (int r = 0; r < 4; ++r)
                        acc[m][ct][r] *= alpha[m][r];
        }

        // P -> LDS (bf16); same-wave region, DS-ordered (no barrier needed)
        #pragma unroll
        for (int m = 0; m < 2; ++m)
            #pragma unroll
            for (int kti = 0; kti < KTI; ++kti)
                #pragma unroll
                for (int r = 0; r < 4; ++r)
                    ps[(w * 32 + m * 16 + quad * 4 + r) * 136 + kti * 16 + l15] = (__bf16)s[m][kti][r];

        // PV: acc[q][c] += P[q][key] * V[c][key]; V B-frags straight from global
        const __bf16* vbase = &vg[((size_t)b * C + c0) * N_PIX + n0];
        #pragma unroll
        for (int kk2 = 0; kk2 < KK2; ++kk2) {
            bf16x8 pa[2];
            #pragma unroll
            for (int m = 0; m < 2; ++m)
                pa[m] = *(const bf16x8*)&ps[(w * 32 + m * 16 + l15) * 136 + kk2 * 32 + quad * 8];
            #pragma unroll
            for (int ct = 0; ct < CT; ++ct) {
                bf16x8 bfr = *(const bf16x8*)&vbase[(size_t)(ct * 16 + l15) * N_PIX + kk2 * 32 + quad * 8];
                #pragma unroll
                for (int m = 0; m < 2; ++m)
                    acc[m][ct] = __builtin_amdgcn_mfma_f32_16x16x32_bf16(pa[m], bfr, acc[m][ct], 0, 0, 0);
            }
        }
    }

    // finalize l (one shfl-reduce), epilogue: coalesced (B,N,C) stores
    float g = gamma[0];
    #pragma unroll
    for (int m = 0; m < 2; ++m)
        #pragma unroll
        for (int r = 0; r < 4; ++r) {
            float l = lp[m][r];
            #pragma unroll
            for (int off = 1; off < 16; off <<= 1) l += __shfl_xor(l, off);
            lp[m][r] = 1.f / l;
        }
    #pragma unroll
    for (int m = 0; m < 2; ++m)
        #pragma unroll
        for (int r = 0; r < 4; ++r) {
            int q = m0 + w * 32 + m * 16 + quad * 4 + r;
            float il = lp[m][r];
            #pragma unroll
            for (int ct = 0; ct < CT; ++ct) {
                int c = c0 + ct * 16 + l15;
                out_t[((size_t)b * N_PIX + q) * C + c] =
                    g * acc[m][ct][r] * il + xin[((size_t)b * C + c) * N_PIX + q];
            }
        }
}

// ---------------------------------------------------------------------------
// Launcher
// ---------------------------------------------------------------------------
extern "C" void kernel_launch(void* const* d_in, const int* in_sizes, int n_in,
                              void* d_out, int out_size, void* d_ws, size_t ws_size,
                              hipStream_t stream) {
    const float* x   = (const float*)d_in[0];
    const float* W1  = (const float*)d_in[1];
    const float* b1  = (const float*)d_in[2];
    const float* u1  = (const float*)d_in[3];
    const float* W2  = (const float*)d_in[4];
    const float* b2  = (const float*)d_in[5];
    const float* u2  = (const float*)d_in[6];
    const float* W3  = (const float*)d_in[7];
    const float* b3  = (const float*)d_in[8];
    const float* u3  = (const float*)d_in[9];
    const float* W4  = (const float*)d_in[10];
    const float* b4  = (const float*)d_in[11];
    const float* u4  = (const float*)d_in[12];
    const float* W5  = (const float*)d_in[13];
    const float* b5  = (const float*)d_in[14];
    const float* u5  = (const float*)d_in[15];
    const float* a1_qW = (const float*)d_in[16];
    const float* a1_qb = (const float*)d_in[17];
    const float* a1_kW = (const float*)d_in[18];
    const float* a1_kb = (const float*)d_in[19];
    const float* a1_vW = (const float*)d_in[20];
    const float* a1_vb = (const float*)d_in[21];
    const float* a1_g  = (const float*)d_in[22];
    const float* a2_qW = (const float*)d_in[23];
    const float* a2_qb = (const float*)d_in[24];
    const float* a2_kW = (const float*)d_in[25];
    const float* a2_kb = (const float*)d_in[26];
    const float* a2_vW = (const float*)d_in[27];
    const float* a2_vb = (const float*)d_in[28];
    const float* a2_g  = (const float*)d_in[29];

    float* ws = (float*)d_ws;
    const size_t SZ_ACT = (size_t)BATCH * 512 * N_PIX;  // 8M floats
    float* sig  = ws;                        // 16
    float* bufA = ws + 16;
    float* bufB = bufA + SZ_ACT;
    float* qf   = bufB + SZ_ACT;                         // 1M fp32
    float* kf   = qf + (size_t)BATCH * 64 * N_PIX;       // 1M fp32
    __bf16* qt  = (__bf16*)(kf + (size_t)BATCH * 64 * N_PIX);  // 1M bf16
    __bf16* ktb = qt + (size_t)BATCH * N_PIX * 64;             // 1M bf16
    __bf16* vb  = ktb + (size_t)BATCH * N_PIX * 64;            // 8M bf16

    dim3 blk(256);

    sigma_kernel<<<1, blk, 0, stream>>>(W1, u1, 64, 6, sig + 0);
    sigma_kernel<<<1, blk, 0, stream>>>(W2, u2, 128, 64, sig + 1);
    sigma_kernel<<<1, blk, 0, stream>>>(W3, u3, 256, 128, sig + 2);
    sigma_kernel<<<1, blk, 0, stream>>>(W4, u4, 512, 256, sig + 3);
    sigma_kernel<<<1, blk, 0, stream>>>(W5, u5, 1, 512, sig + 4);

    conv1x1_kernel<0><<<dim3(64, 1, 4), blk, 0, stream>>>(x, W1, b1, sig + 0, bufA, 6, 64, 1);
    conv1x1_kernel<0><<<dim3(64, 2, 4), blk, 0, stream>>>(bufA, W2, b2, sig + 1, bufB, 64, 128, 1);
    conv1x1_kernel<0><<<dim3(64, 4, 4), blk, 0, stream>>>(bufB, W3, b3, sig + 2, bufA, 128, 256, 1);

    // attention 1 (C=256, Cq=32): bufA -> bufB (transposed (B,N,256))
    conv1x1_kernel<0><<<dim3(64, 1, 4), blk, 0, stream>>>(bufA, a1_qW, a1_qb, nullptr, qf, 256, 32, 0);
    conv1x1_kernel<0><<<dim3(64, 1, 4), blk, 0, stream>>>(bufA, a1_kW, a1_kb, nullptr, kf, 256, 32, 0);
    conv1x1_kernel<1><<<dim3(64, 4, 4), blk, 0, stream>>>(bufA, a1_vW, a1_vb, nullptr, vb, 256, 256, 0);
    transpose_to_bf16<32><<<dim3(64, 4), blk, 0, stream>>>(qf, qt, LOG2E);
    transpose_to_bf16<32><<<dim3(64, 4), blk, 0, stream>>>(kf, ktb, 1.0f);
    attn_fused2<32, 64><<<dim3(32, 4, 4), blk, 0, stream>>>(qt, ktb, vb, bufA, a1_g, bufB, 256);

    // L4: transposed-input conv, bufB (B,N,256) -> bufA (B,512,N)
    conv1x1_t_kernel<<<dim3(64, 8, 4), blk, 0, stream>>>(bufB, W4, b4, sig + 3, bufA, 256, 512, 1);

    // attention 2 (C=512, Cq=64): bufA -> bufB (transposed (B,N,512))
    conv1x1_kernel<0><<<dim3(64, 1, 4), blk, 0, stream>>>(bufA, a2_qW, a2_qb, nullptr, qf, 512, 64, 0);
    conv1x1_kernel<0><<<dim3(64, 1, 4), blk, 0, stream>>>(bufA, a2_kW, a2_kb, nullptr, kf, 512, 64, 0);
    conv1x1_kernel<1><<<dim3(64, 8, 4), blk, 0, stream>>>(bufA, a2_vW, a2_vb, nullptr, vb, 512, 512, 0);
    transpose_to_bf16<64><<<dim3(64, 4), blk, 0, stream>>>(qf, qt, LOG2E);
    transpose_to_bf16<64><<<dim3(64, 4), blk, 0, stream>>>(kf, ktb, 1.0f);
    attn_fused2<64, 128><<<dim3(32, 4, 4), blk, 0, stream>>>(qt, ktb, vb, bufA, a2_g, bufB, 512);

    // L5: transposed-input conv, bufB (B,N,512) -> d_out (B,1,N)
    conv1x1_t_kernel<<<dim3(64, 1, 4), blk, 0, stream>>>(bufB, W5, b5, sig + 4, (float*)d_out, 512, 1, 1);
}

// Round 4
// 1291.459 us; speedup vs baseline: 4.2848x; 1.1814x over previous
//
#include <hip/hip_runtime.h>
#include <math.h>

#define N_PIX 4096  // H*W = 64*64
#define BATCH 4
#define LOG2E 1.4426950408889634f

typedef __bf16 bf16x8 __attribute__((ext_vector_type(8)));
typedef __bf16 bf16x4v __attribute__((ext_vector_type(4)));
typedef float f32x4 __attribute__((ext_vector_type(4)));

// ---------------------------------------------------------------------------
__device__ __forceinline__ float block_reduce_sum(float v, float* red) {
    int t = threadIdx.x;
    red[t] = v;
    __syncthreads();
    for (int s = 128; s > 0; s >>= 1) {
        if (t < s) red[t] += red[t + s];
        __syncthreads();
    }
    float r = red[0];
    __syncthreads();
    return r;
}

// ---------------------------------------------------------------------------
// Spectral norm: one power-iteration -> 1/sigma.
// ---------------------------------------------------------------------------
__global__ __launch_bounds__(256)
void sigma_kernel(const float* __restrict__ W, const float* __restrict__ u,
                  int O, int C, float* __restrict__ out_inv) {
    __shared__ float red[256];
    __shared__ float vsh[512];
    int t = threadIdx.x;
    float part = 0.f;
    for (int c = t; c < C; c += 256) {
        float acc = 0.f;
        for (int o = 0; o < O; ++o) acc += W[o * C + c] * u[o];
        vsh[c] = acc;
        part += acc * acc;
    }
    float nrm2 = block_reduce_sum(part, red);
    float rinv = 1.f / (sqrtf(nrm2) + 1e-12f);
    for (int c = t; c < C; c += 256) vsh[c] *= rinv;
    __syncthreads();
    float part2 = 0.f;
    for (int o = t; o < O; o += 256) {
        float acc = 0.f;
        for (int c = 0; c < C; ++c) acc += W[o * C + c] * vsh[c];
        part2 += acc * acc;
    }
    float ns2 = block_reduce_sum(part2, red);
    if (t == 0) {
        float sig = ns2 / (sqrtf(ns2) + 1e-12f);
        out_inv[0] = 1.f / sig;
    }
}

// ---------------------------------------------------------------------------
// Weight split: (O,C) fp32 * iv * scale -> (O, 2C) bf16  [hi | lo].
// grid.x = O, block 256.
// ---------------------------------------------------------------------------
__global__ __launch_bounds__(256)
void wsplit_kernel(const float* __restrict__ W, const float* __restrict__ iv,
                   float scale, int C, __bf16* __restrict__ out) {
    int o = blockIdx.x;
    float s = (iv ? iv[0] : 1.f) * scale;
    for (int c = threadIdx.x; c < C; c += 256) {
        float wv = W[(size_t)o * C + c] * s;
        __bf16 hi = (__bf16)wv;
        float lo = wv - (float)hi;
        out[(size_t)o * 2 * C + c] = hi;
        out[(size_t)o * 2 * C + C + c] = (__bf16)lo;
    }
}

// ---------------------------------------------------------------------------
// L1 only: fp32 VALU conv (C=6). x (B,C,N) -> out (B,O,N) fp32.
// ---------------------------------------------------------------------------
__global__ __launch_bounds__(256)
void conv_f32_kernel(const float* __restrict__ x, const float* __restrict__ W,
                     const float* __restrict__ bias, const float* __restrict__ sig,
                     float* __restrict__ out, int C, int O, int lrelu) {
    __shared__ float Ws[16][68];
    __shared__ float Xs[16][68];
    int t = threadIdx.x;
    int tx = t & 15, ty = t >> 4;
    int b = blockIdx.z;
    int n0 = blockIdx.x * 64, o0 = blockIdx.y * 64;
    float acc[4][4] = {};
    const float* xb = x + (size_t)b * C * N_PIX;
    for (int c0 = 0; c0 < C; c0 += 16) {
        #pragma unroll
        for (int i = 0; i < 4; ++i) {
            int e = t + i * 256;
            int o = e >> 4, c = e & 15;
            float wv = 0.f;
            if (o0 + o < O && c0 + c < C) wv = W[(size_t)(o0 + o) * C + c0 + c];
            Ws[c][o] = wv;
        }
        #pragma unroll
        for (int i = 0; i < 4; ++i) {
            int e = t + i * 256;
            int c = e >> 6, n = e & 63;
            float xv = 0.f;
            if (c0 + c < C) xv = xb[(size_t)(c0 + c) * N_PIX + n0 + n];
            Xs[c][n] = xv;
        }
        __syncthreads();
        #pragma unroll
        for (int cc = 0; cc < 16; ++cc) {
            float4 wv = *(const float4*)&Ws[cc][ty * 4];
            float4 xv = *(const float4*)&Xs[cc][tx * 4];
            float wa[4] = {wv.x, wv.y, wv.z, wv.w};
            float xa[4] = {xv.x, xv.y, xv.z, xv.w};
            #pragma unroll
            for (int i = 0; i < 4; ++i)
                #pragma unroll
                for (int j = 0; j < 4; ++j)
                    acc[i][j] += wa[i] * xa[j];
        }
        __syncthreads();
    }
    float ivv = sig ? sig[0] : 1.f;
    for (int i = 0; i < 4; ++i) {
        int o = o0 + ty * 4 + i;
        if (o >= O) break;
        float bv = bias[o];
        float vres[4];
        #pragma unroll
        for (int j = 0; j < 4; ++j) {
            float v = acc[i][j] * ivv + bv;
            if (lrelu) v = (v > 0.f) ? v : 0.1f * v;
            vres[j] = v;
        }
        *(float4*)&out[((size_t)b * O + o) * N_PIX + n0 + tx * 4] =
            make_float4(vres[0], vres[1], vres[2], vres[3]);
    }
}

// ---------------------------------------------------------------------------
// Transpose+split: (B,64,N) fp32 -> (B,N,128) bf16 [hi(64)|lo(64)].
// ---------------------------------------------------------------------------
__global__ __launch_bounds__(256)
void tsplit64_kernel(const float* __restrict__ in, __bf16* __restrict__ out) {
    __shared__ float tile[64 * 65];
    int t = threadIdx.x;
    int n0 = blockIdx.x * 64, b = blockIdx.y;
    for (int e = t; e < 64 * 64; e += 256) {
        int c = e >> 6, n = e & 63;
        tile[n * 65 + c] = in[((size_t)b * 64 + c) * N_PIX + n0 + n];
    }
    __syncthreads();
    for (int e = t; e < 64 * 64; e += 256) {
        int n = e >> 6, c = e & 63;
        float v = tile[n * 65 + c];
        __bf16 hi = (__bf16)v;
        size_t base = ((size_t)b * N_PIX + n0 + n) * 128;
        out[base + c] = hi;
        out[base + 64 + c] = (__bf16)(v - (float)hi);
    }
}

// ---------------------------------------------------------------------------
// Split-bf16 MFMA 1x1 conv.
// Input xt: IN_F32 ? (B,N,C) fp32 : (B,N,2C) bf16 split.
// Weights wsp: (O,2C) bf16 split (iv/scale folded in).
// MODE 1: out (B,O,N) bf16 hi      [v-projections]
// MODE 2: out (B,N,2O) bf16 split  [inter-layer activations]
// MODE 4: out (B,N,O)  bf16 hi     [q/k projections]
// Block = 4 waves = WO x WN; wave computes 32 o x 128 n; 3 MFMAs per product
// (hi*hi + hi*lo + lo*hi), fp32 accumulate => ~2^-17 relative error.
// ---------------------------------------------------------------------------
template <int WO, int WN, int MODE, int IN_F32, int LRELU>
__global__ __launch_bounds__(256)
void mfma_conv(const void* __restrict__ xt, const __bf16* __restrict__ wsp,
               const float* __restrict__ bias, float bscale,
               void* __restrict__ outp, int C, int O) {
    constexpr int NT_BLK = WN * 128;
    __shared__ __bf16 Ws[WO * 32 * 72];
    __shared__ __bf16 Xs[NT_BLK * 72];
    int t = threadIdx.x;
    int lane = t & 63, w = t >> 6;
    int l15 = lane & 15, quad = lane >> 4;
    int wo = w / WN, wn = w % WN;
    int b = blockIdx.z;
    int n0b = blockIdx.x * NT_BLK, o0b = blockIdx.y * WO * 32;

    f32x4 acc[2][8] = {};

    for (int c0 = 0; c0 < C; c0 += 32) {
        __syncthreads();
        // stage W tile: WO*32 rows x [hi(32)|lo(32)]
        for (int e = t; e < WO * 32 * 8; e += 256) {
            int row = e >> 3, part = e & 7;
            size_t src = (size_t)(o0b + row) * 2 * C +
                         (part < 4 ? c0 + part * 8 : C + c0 + (part - 4) * 8);
            int dst = row * 72 + (part < 4 ? part * 8 : 32 + (part - 4) * 8);
            *(uint4*)&Ws[dst] = *(const uint4*)&wsp[src];
        }
        // stage X tile: NT_BLK rows x [hi(32)|lo(32)]
        if (IN_F32) {
            const float* xf = (const float*)xt;
            for (int e = t; e < NT_BLK * 8; e += 256) {
                int row = e >> 3, part = e & 7;
                float4 v = *(const float4*)&xf[((size_t)b * N_PIX + n0b + row) * C + c0 + part * 4];
                bf16x4v hi, lo;
                float va[4] = {v.x, v.y, v.z, v.w};
                #pragma unroll
                for (int j = 0; j < 4; ++j) {
                    hi[j] = (__bf16)va[j];
                    lo[j] = (__bf16)(va[j] - (float)hi[j]);
                }
                *(bf16x4v*)&Xs[row * 72 + part * 4] = hi;
                *(bf16x4v*)&Xs[row * 72 + 32 + part * 4] = lo;
            }
        } else {
            const __bf16* xb = (const __bf16*)xt;
            for (int e = t; e < NT_BLK * 8; e += 256) {
                int row = e >> 3, part = e & 7;
                size_t src = ((size_t)b * N_PIX + n0b + row) * 2 * C +
                             (part < 4 ? c0 + part * 8 : C + c0 + (part - 4) * 8);
                int dst = row * 72 + (part < 4 ? part * 8 : 32 + (part - 4) * 8);
                *(uint4*)&Xs[dst] = *(const uint4*)&xb[src];
            }
        }
        __syncthreads();

        bf16x8 ah[2], al[2];
        #pragma unroll
        for (int mf = 0; mf < 2; ++mf) {
            int base = (wo * 32 + mf * 16 + l15) * 72 + quad * 8;
            ah[mf] = *(const bf16x8*)&Ws[base];
            al[mf] = *(const bf16x8*)&Ws[base + 32];
        }
        #pragma unroll
        for (int nt = 0; nt < 8; ++nt) {
            int bbase = (wn * 128 + nt * 16 + l15) * 72 + quad * 8;
            bf16x8 bh = *(const bf16x8*)&Xs[bbase];
            bf16x8 bl = *(const bf16x8*)&Xs[bbase + 32];
            #pragma unroll
            for (int mf = 0; mf < 2; ++mf) {
                acc[mf][nt] = __builtin_amdgcn_mfma_f32_16x16x32_bf16(ah[mf], bh, acc[mf][nt], 0, 0, 0);
                acc[mf][nt] = __builtin_amdgcn_mfma_f32_16x16x32_bf16(ah[mf], bl, acc[mf][nt], 0, 0, 0);
                acc[mf][nt] = __builtin_amdgcn_mfma_f32_16x16x32_bf16(al[mf], bh, acc[mf][nt], 0, 0, 0);
            }
        }
    }

    // epilogue
    float bv[2][4];
    #pragma unroll
    for (int mf = 0; mf < 2; ++mf)
        #pragma unroll
        for (int r = 0; r < 4; ++r)
            bv[mf][r] = bias[o0b + wo * 32 + mf * 16 + quad * 4 + r] * bscale;

    #pragma unroll
    for (int mf = 0; mf < 2; ++mf)
        #pragma unroll
        for (int nt = 0; nt < 8; ++nt) {
            int n = n0b + wn * 128 + nt * 16 + l15;
            float val[4];
            #pragma unroll
            for (int r = 0; r < 4; ++r) {
                float v = acc[mf][nt][r] + bv[mf][r];
                if (LRELU) v = (v > 0.f) ? v : 0.1f * v;
                val[r] = v;
            }
            int obase = o0b + wo * 32 + mf * 16 + quad * 4;
            if (MODE == 1) {
                __bf16* ob = (__bf16*)outp;
                #pragma unroll
                for (int r = 0; r < 4; ++r)
                    ob[((size_t)b * O + obase + r) * N_PIX + n] = (__bf16)val[r];
            } else if (MODE == 2) {
                __bf16* ob = (__bf16*)outp;
                bf16x4v hv, lv;
                #pragma unroll
                for (int r = 0; r < 4; ++r) {
                    hv[r] = (__bf16)val[r];
                    lv[r] = (__bf16)(val[r] - (float)hv[r]);
                }
                size_t rb = ((size_t)b * N_PIX + n) * 2 * O + obase;
                *(bf16x4v*)&ob[rb] = hv;
                *(bf16x4v*)&ob[rb + O] = lv;
            } else {  // MODE 4
                __bf16* ob = (__bf16*)outp;
                bf16x4v hv;
                #pragma unroll
                for (int r = 0; r < 4; ++r) hv[r] = (__bf16)val[r];
                *(bf16x4v*)&ob[((size_t)b * N_PIX + n) * O + obase] = hv;
            }
        }
}

// ---------------------------------------------------------------------------
// Fused flash attention (as round 3), residual from split-bf16 (B,N,2C).
// ---------------------------------------------------------------------------
template <int CQ, int CCH>
__global__ __launch_bounds__(256, 2)
void attn_fused2(const __bf16* __restrict__ qt, const __bf16* __restrict__ kt,
                 const __bf16* __restrict__ vg, const __bf16* __restrict__ xin2,
                 const float* __restrict__ gamma, float* __restrict__ out_t, int C) {
    constexpr int CQP = CQ + 8;
    constexpr int CG = CQ / 8;
    constexpr int KT = 128, KTI = 8, KK2 = 4;
    constexpr int NKK = CQ / 32;
    constexpr int CT = CCH / 16;
    __shared__ __bf16 ks[KT * CQP];
    __shared__ __bf16 ps[128 * 136];
    int t = threadIdx.x;
    int lane = t & 63, w = t >> 6;
    int l15 = lane & 15, quad = lane >> 4;
    int b = blockIdx.z, c0 = blockIdx.y * CCH, m0 = blockIdx.x * 128;

    bf16x8 qf[2][NKK];
    #pragma unroll
    for (int m = 0; m < 2; ++m)
        #pragma unroll
        for (int kk = 0; kk < NKK; ++kk)
            qf[m][kk] = *(const bf16x8*)&qt[((size_t)b * N_PIX + m0 + w * 32 + m * 16 + l15) * CQ + kk * 32 + quad * 8];

    f32x4 acc[2][CT] = {};
    float run_m[2][4], lp[2][4];
    #pragma unroll
    for (int m = 0; m < 2; ++m)
        #pragma unroll
        for (int r = 0; r < 4; ++r) { run_m[m][r] = -1e30f; lp[m][r] = 0.f; }

    for (int n0 = 0; n0 < N_PIX; n0 += KT) {
        __syncthreads();
        for (int e = t; e < KT * CG; e += 256) {
            int row = e / CG, cg = e % CG;
            *(uint4*)&ks[row * CQP + cg * 8] =
                *(const uint4*)&kt[((size_t)b * N_PIX + n0 + row) * CQ + cg * 8];
        }
        __syncthreads();

        f32x4 s[2][KTI] = {};
        #pragma unroll
        for (int kk = 0; kk < NKK; ++kk)
            #pragma unroll
            for (int kti = 0; kti < KTI; ++kti) {
                bf16x8 bfr = *(const bf16x8*)&ks[(kti * 16 + l15) * CQP + kk * 32 + quad * 8];
                #pragma unroll
                for (int m = 0; m < 2; ++m)
                    s[m][kti] = __builtin_amdgcn_mfma_f32_16x16x32_bf16(qf[m][kk], bfr, s[m][kti], 0, 0, 0);
            }

        bool need = false;
        float alpha[2][4];
        #pragma unroll
        for (int m = 0; m < 2; ++m)
            #pragma unroll
            for (int r = 0; r < 4; ++r) {
                float tm = s[m][0][r];
                #pragma unroll
                for (int kti = 1; kti < KTI; ++kti) tm = fmaxf(tm, s[m][kti][r]);
                #pragma unroll
                for (int off = 1; off < 16; off <<= 1) tm = fmaxf(tm, __shfl_xor(tm, off));
                float nm = fmaxf(run_m[m][r], tm);
                float a = exp2f(run_m[m][r] - nm);
                alpha[m][r] = a;
                need = need || (a < 1.0f);
                run_m[m][r] = nm;
                float psum = 0.f;
                #pragma unroll
                for (int kti = 0; kti < KTI; ++kti) {
                    float p = exp2f(s[m][kti][r] - nm);
                    s[m][kti][r] = p;
                    psum += p;
                }
                lp[m][r] = lp[m][r] * a + psum;
            }
        if (__ballot(need)) {
            #pragma unroll
            for (int m = 0; m < 2; ++m)
                #pragma unroll
                for (int ct = 0; ct < CT; ++ct)
                    #pragma unroll
                    for (int r = 0; r < 4; ++r)
                        acc[m][ct][r] *= alpha[m][r];
        }

        #pragma unroll
        for (int m = 0; m < 2; ++m)
            #pragma unroll
            for (int kti = 0; kti < KTI; ++kti)
                #pragma unroll
                for (int r = 0; r < 4; ++r)
                    ps[(w * 32 + m * 16 + quad * 4 + r) * 136 + kti * 16 + l15] = (__bf16)s[m][kti][r];

        const __bf16* vbase = &vg[((size_t)b * C + c0) * N_PIX + n0];
        #pragma unroll
        for (int kk2 = 0; kk2 < KK2; ++kk2) {
            bf16x8 pa[2];
            #pragma unroll
            for (int m = 0; m < 2; ++m)
                pa[m] = *(const bf16x8*)&ps[(w * 32 + m * 16 + l15) * 136 + kk2 * 32 + quad * 8];
            #pragma unroll
            for (int ct = 0; ct < CT; ++ct) {
                bf16x8 bfr = *(const bf16x8*)&vbase[(size_t)(ct * 16 + l15) * N_PIX + kk2 * 32 + quad * 8];
                #pragma unroll
                for (int m = 0; m < 2; ++m)
                    acc[m][ct] = __builtin_amdgcn_mfma_f32_16x16x32_bf16(pa[m], bfr, acc[m][ct], 0, 0, 0);
            }
        }
    }

    float g = gamma[0];
    #pragma unroll
    for (int m = 0; m < 2; ++m)
        #pragma unroll
        for (int r = 0; r < 4; ++r) {
            float l = lp[m][r];
            #pragma unroll
            for (int off = 1; off < 16; off <<= 1) l += __shfl_xor(l, off);
            lp[m][r] = 1.f / l;
        }
    #pragma unroll
    for (int m = 0; m < 2; ++m)
        #pragma unroll
        for (int r = 0; r < 4; ++r) {
            int q = m0 + w * 32 + m * 16 + quad * 4 + r;
            float il = lp[m][r];
            size_t xb = ((size_t)b * N_PIX + q) * 2 * C;
            #pragma unroll
            for (int ct = 0; ct < CT; ++ct) {
                int c = c0 + ct * 16 + l15;
                float xr = (float)xin2[xb + c] + (float)xin2[xb + C + c];
                out_t[((size_t)b * N_PIX + q) * C + c] = g * acc[m][ct][r] * il + xr;
            }
        }
}

// ---------------------------------------------------------------------------
// L5: out[b,n] = lrelu(iv * dot(W5, h[b,n,:]) + b5).  h: (B,N,512) fp32.
// One wave per pixel; 4 pixels per block.
// ---------------------------------------------------------------------------
__global__ __launch_bounds__(256)
void l5_kernel(const float* __restrict__ h, const float* __restrict__ W5,
               const float* __restrict__ b5, const float* __restrict__ sig,
               float* __restrict__ out) {
    int t = threadIdx.x;
    int lane = t & 63, w = t >> 6;
    int p = blockIdx.x * 4 + w;
    const float* row = h + (size_t)p * 512;
    float4 a0 = *(const float4*)&row[lane * 8];
    float4 a1 = *(const float4*)&row[lane * 8 + 4];
    float4 w0 = *(const float4*)&W5[lane * 8];
    float4 w1 = *(const float4*)&W5[lane * 8 + 4];
    float s = a0.x * w0.x + a0.y * w0.y + a0.z * w0.z + a0.w * w0.w +
              a1.x * w1.x + a1.y * w1.y + a1.z * w1.z + a1.w * w1.w;
    #pragma unroll
    for (int off = 1; off < 64; off <<= 1) s += __shfl_xor(s, off);
    if (lane == 0) {
        float v = sig[0] * s + b5[0];
        out[p] = (v > 0.f) ? v : 0.1f * v;
    }
}

// ---------------------------------------------------------------------------
// Launcher
// ---------------------------------------------------------------------------
extern "C" void kernel_launch(void* const* d_in, const int* in_sizes, int n_in,
                              void* d_out, int out_size, void* d_ws, size_t ws_size,
                              hipStream_t stream) {
    const float* x   = (const float*)d_in[0];
    const float* W1  = (const float*)d_in[1];
    const float* b1  = (const float*)d_in[2];
    const float* u1  = (const float*)d_in[3];
    const float* W2  = (const float*)d_in[4];
    const float* b2  = (const float*)d_in[5];
    const float* u2  = (const float*)d_in[6];
    const float* W3  = (const float*)d_in[7];
    const float* b3  = (const float*)d_in[8];
    const float* u3  = (const float*)d_in[9];
    const float* W4  = (const float*)d_in[10];
    const float* b4  = (const float*)d_in[11];
    const float* u4  = (const float*)d_in[12];
    const float* W5  = (const float*)d_in[13];
    const float* b5  = (const float*)d_in[14];
    const float* u5  = (const float*)d_in[15];
    const float* a1_qW = (const float*)d_in[16];
    const float* a1_qb = (const float*)d_in[17];
    const float* a1_kW = (const float*)d_in[18];
    const float* a1_kb = (const float*)d_in[19];
    const float* a1_vW = (const float*)d_in[20];
    const float* a1_vb = (const float*)d_in[21];
    const float* a1_g  = (const float*)d_in[22];
    const float* a2_qW = (const float*)d_in[23];
    const float* a2_qb = (const float*)d_in[24];
    const float* a2_kW = (const float*)d_in[25];
    const float* a2_kb = (const float*)d_in[26];
    const float* a2_vW = (const float*)d_in[27];
    const float* a2_vb = (const float*)d_in[28];
    const float* a2_g  = (const float*)d_in[29];

    float* ws = (float*)d_ws;
    const size_t NF = (size_t)BATCH * N_PIX;  // 16384
    float* sig    = ws;                       // 16
    float* h1     = ws + 16;                  // NF*64 fl
    float* slabC  = h1 + NF * 64;             // NF*512 fl
    float* slabS1 = slabC + NF * 512;         // NF*256 fl
    float* slabS2 = slabS1 + NF * 256;        // NF*512 fl
    float* qtf    = slabS2 + NF * 512;        // NF*32 fl
    float* ktf    = qtf + NF * 32;            // NF*32 fl
    float* wspf   = ktf + NF * 32;            // ~0.6M fl

    __bf16* h1t = (__bf16*)slabS1;            // (B,N,128)
    __bf16* h2t = (__bf16*)slabS2;            // (B,N,256)
    __bf16* h3t = (__bf16*)slabS1;            // (B,N,512)
    __bf16* h5t = (__bf16*)slabS2;            // (B,N,1024)
    float*  h4t = slabC;                      // (B,N,256) fp32
    __bf16* vb1 = (__bf16*)(slabC + NF * 256);// (B,256,N)
    float*  h6t = slabC;                      // (B,N,512) fp32
    __bf16* vb2 = (__bf16*)slabS1;            // (B,512,N)
    __bf16* qt  = (__bf16*)qtf;
    __bf16* ktb = (__bf16*)ktf;
    __bf16* wsp = (__bf16*)wspf;

    __bf16* wsL2  = wsp;            // 128*128
    __bf16* wsL3  = wsL2 + 16384;   // 256*256
    __bf16* wsL4  = wsL3 + 65536;   // 512*512
    __bf16* wsA1q = wsL4 + 262144;  // 32*512
    __bf16* wsA1k = wsA1q + 16384;
    __bf16* wsA1v = wsA1k + 16384;  // 256*512
    __bf16* wsA2q = wsA1v + 131072; // 64*1024
    __bf16* wsA2k = wsA2q + 65536;
    __bf16* wsA2v = wsA2k + 65536;  // 512*1024

    dim3 blk(256);

    sigma_kernel<<<1, blk, 0, stream>>>(W1, u1, 64, 6, sig + 0);
    sigma_kernel<<<1, blk, 0, stream>>>(W2, u2, 128, 64, sig + 1);
    sigma_kernel<<<1, blk, 0, stream>>>(W3, u3, 256, 128, sig + 2);
    sigma_kernel<<<1, blk, 0, stream>>>(W4, u4, 512, 256, sig + 3);
    sigma_kernel<<<1, blk, 0, stream>>>(W5, u5, 1, 512, sig + 4);

    wsplit_kernel<<<128, blk, 0, stream>>>(W2, sig + 1, 1.f, 64, wsL2);
    wsplit_kernel<<<256, blk, 0, stream>>>(W3, sig + 2, 1.f, 128, wsL3);
    wsplit_kernel<<<512, blk, 0, stream>>>(W4, sig + 3, 1.f, 256, wsL4);
    wsplit_kernel<<<32,  blk, 0, stream>>>(a1_qW, nullptr, LOG2E, 256, wsA1q);
    wsplit_kernel<<<32,  blk, 0, stream>>>(a1_kW, nullptr, 1.f, 256, wsA1k);
    wsplit_kernel<<<256, blk, 0, stream>>>(a1_vW, nullptr, 1.f, 256, wsA1v);
    wsplit_kernel<<<64,  blk, 0, stream>>>(a2_qW, nullptr, LOG2E, 512, wsA2q);
    wsplit_kernel<<<64,  blk, 0, stream>>>(a2_kW, nullptr, 1.f, 512, wsA2k);
    wsplit_kernel<<<512, blk, 0, stream>>>(a2_vW, nullptr, 1.f, 512, wsA2v);

    // L1 (fp32) + transpose/split
    conv_f32_kernel<<<dim3(64, 1, 4), blk, 0, stream>>>(x, W1, b1, sig + 0, h1, 6, 64, 1);
    tsplit64_kernel<<<dim3(64, 4), blk, 0, stream>>>(h1, h1t);

    // L2, L3 (split-MFMA)
    mfma_conv<4, 1, 2, 0, 1><<<dim3(32, 1, 4), blk, 0, stream>>>(h1t, wsL2, b2, 1.f, h2t, 64, 128);
    mfma_conv<4, 1, 2, 0, 1><<<dim3(32, 2, 4), blk, 0, stream>>>(h2t, wsL3, b3, 1.f, h3t, 128, 256);

    // attention 1
    mfma_conv<1, 4, 4, 0, 0><<<dim3(8, 1, 4), blk, 0, stream>>>(h3t, wsA1q, a1_qb, LOG2E, qt, 256, 32);
    mfma_conv<1, 4, 4, 0, 0><<<dim3(8, 1, 4), blk, 0, stream>>>(h3t, wsA1k, a1_kb, 1.f, ktb, 256, 32);
    mfma_conv<4, 1, 1, 0, 0><<<dim3(32, 2, 4), blk, 0, stream>>>(h3t, wsA1v, a1_vb, 1.f, vb1, 256, 256);
    attn_fused2<32, 64><<<dim3(32, 4, 4), blk, 0, stream>>>(qt, ktb, vb1, h3t, a1_g, h4t, 256);

    // L4 (fp32-transposed input)
    mfma_conv<4, 1, 2, 1, 1><<<dim3(32, 4, 4), blk, 0, stream>>>(h4t, wsL4, b4, 1.f, h5t, 256, 512);

    // attention 2
    mfma_conv<2, 2, 4, 0, 0><<<dim3(16, 1, 4), blk, 0, stream>>>(h5t, wsA2q, a2_qb, LOG2E, qt, 512, 64);
    mfma_conv<2, 2, 4, 0, 0><<<dim3(16, 1, 4), blk, 0, stream>>>(h5t, wsA2k, a2_kb, 1.f, ktb, 512, 64);
    mfma_conv<4, 1, 1, 0, 0><<<dim3(32, 4, 4), blk, 0, stream>>>(h5t, wsA2v, a2_vb, 1.f, vb2, 512, 512);
    attn_fused2<64, 128><<<dim3(32, 4, 4), blk, 0, stream>>>(qt, ktb, vb2, h5t, a2_g, h6t, 512);

    // L5
    l5_kernel<<<4096, blk, 0, stream>>>(h6t, W5, b5, sig + 4, (float*)d_out);
}

// Round 5
// 1234.393 us; speedup vs baseline: 4.4829x; 1.0462x over previous
//
#include <hip/hip_runtime.h>
#include <math.h>

#define N_PIX 4096  // H*W = 64*64
#define BATCH 4
#define LOG2E 1.4426950408889634f

typedef __bf16 bf16x8 __attribute__((ext_vector_type(8)));
typedef __bf16 bf16x4v __attribute__((ext_vector_type(4)));
typedef float f32x4 __attribute__((ext_vector_type(4)));

// ---------------------------------------------------------------------------
__device__ __forceinline__ float block_reduce_sum(float v, float* red) {
    int t = threadIdx.x;
    red[t] = v;
    __syncthreads();
    for (int s = 128; s > 0; s >>= 1) {
        if (t < s) red[t] += red[t + s];
        __syncthreads();
    }
    float r = red[0];
    __syncthreads();
    return r;
}

// ---------------------------------------------------------------------------
// Spectral norm: one power-iteration -> 1/sigma.
// ---------------------------------------------------------------------------
__global__ __launch_bounds__(256)
void sigma_kernel(const float* __restrict__ W, const float* __restrict__ u,
                  int O, int C, float* __restrict__ out_inv) {
    __shared__ float red[256];
    __shared__ float vsh[512];
    int t = threadIdx.x;
    float part = 0.f;
    for (int c = t; c < C; c += 256) {
        float acc = 0.f;
        for (int o = 0; o < O; ++o) acc += W[o * C + c] * u[o];
        vsh[c] = acc;
        part += acc * acc;
    }
    float nrm2 = block_reduce_sum(part, red);
    float rinv = 1.f / (sqrtf(nrm2) + 1e-12f);
    for (int c = t; c < C; c += 256) vsh[c] *= rinv;
    __syncthreads();
    float part2 = 0.f;
    for (int o = t; o < O; o += 256) {
        float acc = 0.f;
        for (int c = 0; c < C; ++c) acc += W[o * C + c] * vsh[c];
        part2 += acc * acc;
    }
    float ns2 = block_reduce_sum(part2, red);
    if (t == 0) {
        float sig = ns2 / (sqrtf(ns2) + 1e-12f);
        out_inv[0] = 1.f / sig;
    }
}

// ---------------------------------------------------------------------------
// Weight split: (O,C) fp32 * iv * scale -> (O, 2C) bf16  [hi | lo].
// ---------------------------------------------------------------------------
__global__ __launch_bounds__(256)
void wsplit_kernel(const float* __restrict__ W, const float* __restrict__ iv,
                   float scale, int C, __bf16* __restrict__ out) {
    int o = blockIdx.x;
    float s = (iv ? iv[0] : 1.f) * scale;
    for (int c = threadIdx.x; c < C; c += 256) {
        float wv = W[(size_t)o * C + c] * s;
        __bf16 hi = (__bf16)wv;
        float lo = wv - (float)hi;
        out[(size_t)o * 2 * C + c] = hi;
        out[(size_t)o * 2 * C + C + c] = (__bf16)lo;
    }
}

// ---------------------------------------------------------------------------
// L1 only: fp32 VALU conv (C=6). x (B,C,N) -> out (B,O,N) fp32.
// ---------------------------------------------------------------------------
__global__ __launch_bounds__(256)
void conv_f32_kernel(const float* __restrict__ x, const float* __restrict__ W,
                     const float* __restrict__ bias, const float* __restrict__ sig,
                     float* __restrict__ out, int C, int O, int lrelu) {
    __shared__ float Ws[16][68];
    __shared__ float Xs[16][68];
    int t = threadIdx.x;
    int tx = t & 15, ty = t >> 4;
    int b = blockIdx.z;
    int n0 = blockIdx.x * 64, o0 = blockIdx.y * 64;
    float acc[4][4] = {};
    const float* xb = x + (size_t)b * C * N_PIX;
    for (int c0 = 0; c0 < C; c0 += 16) {
        #pragma unroll
        for (int i = 0; i < 4; ++i) {
            int e = t + i * 256;
            int o = e >> 4, c = e & 15;
            float wv = 0.f;
            if (o0 + o < O && c0 + c < C) wv = W[(size_t)(o0 + o) * C + c0 + c];
            Ws[c][o] = wv;
        }
        #pragma unroll
        for (int i = 0; i < 4; ++i) {
            int e = t + i * 256;
            int c = e >> 6, n = e & 63;
            float xv = 0.f;
            if (c0 + c < C) xv = xb[(size_t)(c0 + c) * N_PIX + n0 + n];
            Xs[c][n] = xv;
        }
        __syncthreads();
        #pragma unroll
        for (int cc = 0; cc < 16; ++cc) {
            float4 wv = *(const float4*)&Ws[cc][ty * 4];
            float4 xv = *(const float4*)&Xs[cc][tx * 4];
            float wa[4] = {wv.x, wv.y, wv.z, wv.w};
            float xa[4] = {xv.x, xv.y, xv.z, xv.w};
            #pragma unroll
            for (int i = 0; i < 4; ++i)
                #pragma unroll
                for (int j = 0; j < 4; ++j)
                    acc[i][j] += wa[i] * xa[j];
        }
        __syncthreads();
    }
    float ivv = sig ? sig[0] : 1.f;
    for (int i = 0; i < 4; ++i) {
        int o = o0 + ty * 4 + i;
        if (o >= O) break;
        float bv = bias[o];
        float vres[4];
        #pragma unroll
        for (int j = 0; j < 4; ++j) {
            float v = acc[i][j] * ivv + bv;
            if (lrelu) v = (v > 0.f) ? v : 0.1f * v;
            vres[j] = v;
        }
        *(float4*)&out[((size_t)b * O + o) * N_PIX + n0 + tx * 4] =
            make_float4(vres[0], vres[1], vres[2], vres[3]);
    }
}

// ---------------------------------------------------------------------------
// Transpose+split: (B,64,N) fp32 -> (B,N,128) bf16 [hi(64)|lo(64)].
// ---------------------------------------------------------------------------
__global__ __launch_bounds__(256)
void tsplit64_kernel(const float* __restrict__ in, __bf16* __restrict__ out) {
    __shared__ float tile[64 * 65];
    int t = threadIdx.x;
    int n0 = blockIdx.x * 64, b = blockIdx.y;
    for (int e = t; e < 64 * 64; e += 256) {
        int c = e >> 6, n = e & 63;
        tile[n * 65 + c] = in[((size_t)b * 64 + c) * N_PIX + n0 + n];
    }
    __syncthreads();
    for (int e = t; e < 64 * 64; e += 256) {
        int n = e >> 6, c = e & 63;
        float v = tile[n * 65 + c];
        __bf16 hi = (__bf16)v;
        size_t base = ((size_t)b * N_PIX + n0 + n) * 128;
        out[base + c] = hi;
        out[base + 64 + c] = (__bf16)(v - (float)hi);
    }
}

// ---------------------------------------------------------------------------
// Split-bf16 MFMA 1x1 conv (unchanged from round 4).
// ---------------------------------------------------------------------------
template <int WO, int WN, int MODE, int IN_F32, int LRELU>
__global__ __launch_bounds__(256)
void mfma_conv(const void* __restrict__ xt, const __bf16* __restrict__ wsp,
               const float* __restrict__ bias, float bscale,
               void* __restrict__ outp, int C, int O) {
    constexpr int NT_BLK = WN * 128;
    __shared__ __bf16 Ws[WO * 32 * 72];
    __shared__ __bf16 Xs[NT_BLK * 72];
    int t = threadIdx.x;
    int lane = t & 63, w = t >> 6;
    int l15 = lane & 15, quad = lane >> 4;
    int wo = w / WN, wn = w % WN;
    int b = blockIdx.z;
    int n0b = blockIdx.x * NT_BLK, o0b = blockIdx.y * WO * 32;

    f32x4 acc[2][8] = {};

    for (int c0 = 0; c0 < C; c0 += 32) {
        __syncthreads();
        for (int e = t; e < WO * 32 * 8; e += 256) {
            int row = e >> 3, part = e & 7;
            size_t src = (size_t)(o0b + row) * 2 * C +
                         (part < 4 ? c0 + part * 8 : C + c0 + (part - 4) * 8);
            int dst = row * 72 + (part < 4 ? part * 8 : 32 + (part - 4) * 8);
            *(uint4*)&Ws[dst] = *(const uint4*)&wsp[src];
        }
        if (IN_F32) {
            const float* xf = (const float*)xt;
            for (int e = t; e < NT_BLK * 8; e += 256) {
                int row = e >> 3, part = e & 7;
                float4 v = *(const float4*)&xf[((size_t)b * N_PIX + n0b + row) * C + c0 + part * 4];
                bf16x4v hi, lo;
                float va[4] = {v.x, v.y, v.z, v.w};
                #pragma unroll
                for (int j = 0; j < 4; ++j) {
                    hi[j] = (__bf16)va[j];
                    lo[j] = (__bf16)(va[j] - (float)hi[j]);
                }
                *(bf16x4v*)&Xs[row * 72 + part * 4] = hi;
                *(bf16x4v*)&Xs[row * 72 + 32 + part * 4] = lo;
            }
        } else {
            const __bf16* xb = (const __bf16*)xt;
            for (int e = t; e < NT_BLK * 8; e += 256) {
                int row = e >> 3, part = e & 7;
                size_t src = ((size_t)b * N_PIX + n0b + row) * 2 * C +
                             (part < 4 ? c0 + part * 8 : C + c0 + (part - 4) * 8);
                int dst = row * 72 + (part < 4 ? part * 8 : 32 + (part - 4) * 8);
                *(uint4*)&Xs[dst] = *(const uint4*)&xb[src];
            }
        }
        __syncthreads();

        bf16x8 ah[2], al[2];
        #pragma unroll
        for (int mf = 0; mf < 2; ++mf) {
            int base = (wo * 32 + mf * 16 + l15) * 72 + quad * 8;
            ah[mf] = *(const bf16x8*)&Ws[base];
            al[mf] = *(const bf16x8*)&Ws[base + 32];
        }
        #pragma unroll
        for (int nt = 0; nt < 8; ++nt) {
            int bbase = (wn * 128 + nt * 16 + l15) * 72 + quad * 8;
            bf16x8 bh = *(const bf16x8*)&Xs[bbase];
            bf16x8 bl = *(const bf16x8*)&Xs[bbase + 32];
            #pragma unroll
            for (int mf = 0; mf < 2; ++mf) {
                acc[mf][nt] = __builtin_amdgcn_mfma_f32_16x16x32_bf16(ah[mf], bh, acc[mf][nt], 0, 0, 0);
                acc[mf][nt] = __builtin_amdgcn_mfma_f32_16x16x32_bf16(ah[mf], bl, acc[mf][nt], 0, 0, 0);
                acc[mf][nt] = __builtin_amdgcn_mfma_f32_16x16x32_bf16(al[mf], bh, acc[mf][nt], 0, 0, 0);
            }
        }
    }

    float bv[2][4];
    #pragma unroll
    for (int mf = 0; mf < 2; ++mf)
        #pragma unroll
        for (int r = 0; r < 4; ++r)
            bv[mf][r] = bias[o0b + wo * 32 + mf * 16 + quad * 4 + r] * bscale;

    #pragma unroll
    for (int mf = 0; mf < 2; ++mf)
        #pragma unroll
        for (int nt = 0; nt < 8; ++nt) {
            int n = n0b + wn * 128 + nt * 16 + l15;
            float val[4];
            #pragma unroll
            for (int r = 0; r < 4; ++r) {
                float v = acc[mf][nt][r] + bv[mf][r];
                if (LRELU) v = (v > 0.f) ? v : 0.1f * v;
                val[r] = v;
            }
            int obase = o0b + wo * 32 + mf * 16 + quad * 4;
            if (MODE == 1) {
                __bf16* ob = (__bf16*)outp;
                #pragma unroll
                for (int r = 0; r < 4; ++r)
                    ob[((size_t)b * O + obase + r) * N_PIX + n] = (__bf16)val[r];
            } else if (MODE == 2) {
                __bf16* ob = (__bf16*)outp;
                bf16x4v hv, lv;
                #pragma unroll
                for (int r = 0; r < 4; ++r) {
                    hv[r] = (__bf16)val[r];
                    lv[r] = (__bf16)(val[r] - (float)hv[r]);
                }
                size_t rb = ((size_t)b * N_PIX + n) * 2 * O + obase;
                *(bf16x4v*)&ob[rb] = hv;
                *(bf16x4v*)&ob[rb + O] = lv;
            } else {  // MODE 4
                __bf16* ob = (__bf16*)outp;
                bf16x4v hv;
                #pragma unroll
                for (int r = 0; r < 4; ++r) hv[r] = (__bf16)val[r];
                *(bf16x4v*)&ob[((size_t)b * N_PIX + n) * O + obase] = hv;
            }
        }
}

// ---------------------------------------------------------------------------
// Flash attention v3: transposed score tile S^T = K.Q^T.
// qt/kt: (B,N,CQ) bf16 (qt pre-scaled by log2e). vg: (B,C,N) bf16.
// xin2: (B,N,2C) split-bf16 residual. out_t: (B,N,C) fp32.
// Block = 4 waves, each 32 queries (2 m-frags of 16) x CCH channels; M=128.
// Per lane: query = l15 -> softmax state (m,l) is a per-lane SCALAR.
// K and V A-frags direct from global (identical across waves -> L1).
// P round-trip: ds_write_b64 / ds_read_b128, wave-private, NO barriers.
// Grid: 1-D 512, XCD-swizzled so each (batch,c-slice) V-slab stays in one L2.
// ---------------------------------------------------------------------------
template <int CQ, int CCH>
__global__ __launch_bounds__(256)
void attn_fused3(const __bf16* __restrict__ qt, const __bf16* __restrict__ kt,
                 const __bf16* __restrict__ vg, const __bf16* __restrict__ xin2,
                 const float* __restrict__ gamma, float* __restrict__ out_t, int C) {
    constexpr int NKK = CQ / 32;
    constexpr int CT = CCH / 16;
    constexpr int PSTR = 72;
    __shared__ __bf16 ps[4 * 32 * PSTR];
    int t = threadIdx.x;
    int lane = t & 63, w = t >> 6;
    int l15 = lane & 15, quad = lane >> 4;
    // XCD-aware decode: pair=(b,cblk) pinned to one XCD, m-blocks spread in it
    int bid = blockIdx.x;
    int xcd = bid & 7, jj = bid >> 3;
    int pair = (jj & 1) * 8 + xcd;
    int mblk = jj >> 1;
    int b = pair >> 2, cblk = pair & 3;
    int c0 = cblk * CCH, m0 = mblk * 128;
    int q0 = m0 + w * 32;

    bf16x8 qf[2][NKK];
    #pragma unroll
    for (int m = 0; m < 2; ++m)
        #pragma unroll
        for (int kk = 0; kk < NKK; ++kk)
            qf[m][kk] = *(const bf16x8*)&qt[((size_t)b * N_PIX + q0 + m * 16 + l15) * CQ + kk * 32 + quad * 8];

    const __bf16* kb = kt + (size_t)b * N_PIX * CQ;
    const __bf16* vbase = vg + ((size_t)b * C + c0) * (size_t)N_PIX;
    __bf16* psw = ps + w * 32 * PSTR;

    f32x4 acc[2][CT] = {};
    float run_m[2] = {-1e30f, -1e30f}, lsum[2] = {0.f, 0.f};

    for (int n0 = 0; n0 < N_PIX; n0 += 64) {
        // S^T tiles: D[key=quad*4+r][query=l15]
        f32x4 s[2][4] = {};
        #pragma unroll
        for (int tt = 0; tt < 4; ++tt) {
            bf16x8 kf[NKK];
            #pragma unroll
            for (int kk = 0; kk < NKK; ++kk)
                kf[kk] = *(const bf16x8*)&kb[(size_t)(n0 + tt * 16 + l15) * CQ + kk * 32 + quad * 8];
            #pragma unroll
            for (int kk = 0; kk < NKK; ++kk)
                #pragma unroll
                for (int m = 0; m < 2; ++m)
                    s[m][tt] = __builtin_amdgcn_mfma_f32_16x16x32_bf16(kf[kk], qf[m][kk], s[m][tt], 0, 0, 0);
        }
        // online softmax; per-lane scalar state (query = l15)
        bool need = false;
        float alpha[2];
        #pragma unroll
        for (int m = 0; m < 2; ++m) {
            float tm = -1e30f;
            #pragma unroll
            for (int tt = 0; tt < 4; ++tt)
                #pragma unroll
                for (int r = 0; r < 4; ++r) tm = fmaxf(tm, s[m][tt][r]);
            tm = fmaxf(tm, __shfl_xor(tm, 16));
            tm = fmaxf(tm, __shfl_xor(tm, 32));
            float nm = fmaxf(run_m[m], tm);
            alpha[m] = exp2f(run_m[m] - nm);
            run_m[m] = nm;
            need = need || (alpha[m] < 1.f);
            float psum = 0.f;
            #pragma unroll
            for (int tt = 0; tt < 4; ++tt) {
                bf16x4v pk;
                #pragma unroll
                for (int r = 0; r < 4; ++r) {
                    float p = exp2f(s[m][tt][r] - nm);
                    psum += p;
                    pk[r] = (__bf16)p;
                }
                // P[query][key]: 4 consecutive keys -> one b64 write
                *(bf16x4v*)&psw[(m * 16 + l15) * PSTR + tt * 16 + quad * 4] = pk;
            }
            lsum[m] = lsum[m] * alpha[m] + psum;
        }
        if (__ballot(need)) {
            #pragma unroll
            for (int m = 0; m < 2; ++m)
                #pragma unroll
                for (int ct = 0; ct < CT; ++ct)
                    #pragma unroll
                    for (int r = 0; r < 4; ++r) acc[m][ct][r] *= alpha[m];
        }
        // PV: O^T[c][q] += V[c][key] . P^T[key][q]
        #pragma unroll
        for (int kk2 = 0; kk2 < 2; ++kk2) {
            bf16x8 pf[2];
            #pragma unroll
            for (int m = 0; m < 2; ++m)
                pf[m] = *(const bf16x8*)&psw[(m * 16 + l15) * PSTR + kk2 * 32 + quad * 8];
            #pragma unroll
            for (int ct = 0; ct < CT; ++ct) {
                bf16x8 vf = *(const bf16x8*)&vbase[(size_t)(ct * 16 + l15) * N_PIX + n0 + kk2 * 32 + quad * 8];
                #pragma unroll
                for (int m = 0; m < 2; ++m)
                    acc[m][ct] = __builtin_amdgcn_mfma_f32_16x16x32_bf16(vf, pf[m], acc[m][ct], 0, 0, 0);
            }
        }
    }

    float g = gamma[0];
    #pragma unroll
    for (int m = 0; m < 2; ++m) {
        float l = lsum[m];
        l += __shfl_xor(l, 16);
        l += __shfl_xor(l, 32);
        lsum[m] = 1.f / l;
    }
    // epilogue: acc D[c=quad*4+r][q=l15]; 4 consecutive c -> float4 store
    #pragma unroll
    for (int m = 0; m < 2; ++m) {
        int q = q0 + m * 16 + l15;
        size_t xrb = ((size_t)b * N_PIX + q) * 2 * C;
        size_t orb = ((size_t)b * N_PIX + q) * C;
        float il = lsum[m];
        #pragma unroll
        for (int ct = 0; ct < CT; ++ct) {
            int cb = c0 + ct * 16 + quad * 4;
            bf16x4v hi = *(const bf16x4v*)&xin2[xrb + cb];
            bf16x4v lo = *(const bf16x4v*)&xin2[xrb + C + cb];
            float o[4];
            #pragma unroll
            for (int r = 0; r < 4; ++r)
                o[r] = g * acc[m][ct][r] * il + ((float)hi[r] + (float)lo[r]);
            *(float4*)&out_t[orb + cb] = make_float4(o[0], o[1], o[2], o[3]);
        }
    }
}

// ---------------------------------------------------------------------------
// L5: out[b,n] = lrelu(iv * dot(W5, h[b,n,:]) + b5).  h: (B,N,512) fp32.
// ---------------------------------------------------------------------------
__global__ __launch_bounds__(256)
void l5_kernel(const float* __restrict__ h, const float* __restrict__ W5,
               const float* __restrict__ b5, const float* __restrict__ sig,
               float* __restrict__ out) {
    int t = threadIdx.x;
    int lane = t & 63, w = t >> 6;
    int p = blockIdx.x * 4 + w;
    const float* row = h + (size_t)p * 512;
    float4 a0 = *(const float4*)&row[lane * 8];
    float4 a1 = *(const float4*)&row[lane * 8 + 4];
    float4 w0 = *(const float4*)&W5[lane * 8];
    float4 w1 = *(const float4*)&W5[lane * 8 + 4];
    float s = a0.x * w0.x + a0.y * w0.y + a0.z * w0.z + a0.w * w0.w +
              a1.x * w1.x + a1.y * w1.y + a1.z * w1.z + a1.w * w1.w;
    #pragma unroll
    for (int off = 1; off < 64; off <<= 1) s += __shfl_xor(s, off);
    if (lane == 0) {
        float v = sig[0] * s + b5[0];
        out[p] = (v > 0.f) ? v : 0.1f * v;
    }
}

// ---------------------------------------------------------------------------
// Launcher
// ---------------------------------------------------------------------------
extern "C" void kernel_launch(void* const* d_in, const int* in_sizes, int n_in,
                              void* d_out, int out_size, void* d_ws, size_t ws_size,
                              hipStream_t stream) {
    const float* x   = (const float*)d_in[0];
    const float* W1  = (const float*)d_in[1];
    const float* b1  = (const float*)d_in[2];
    const float* u1  = (const float*)d_in[3];
    const float* W2  = (const float*)d_in[4];
    const float* b2  = (const float*)d_in[5];
    const float* u2  = (const float*)d_in[6];
    const float* W3  = (const float*)d_in[7];
    const float* b3  = (const float*)d_in[8];
    const float* u3  = (const float*)d_in[9];
    const float* W4  = (const float*)d_in[10];
    const float* b4  = (const float*)d_in[11];
    const float* u4  = (const float*)d_in[12];
    const float* W5  = (const float*)d_in[13];
    const float* b5  = (const float*)d_in[14];
    const float* u5  = (const float*)d_in[15];
    const float* a1_qW = (const float*)d_in[16];
    const float* a1_qb = (const float*)d_in[17];
    const float* a1_kW = (const float*)d_in[18];
    const float* a1_kb = (const float*)d_in[19];
    const float* a1_vW = (const float*)d_in[20];
    const float* a1_vb = (const float*)d_in[21];
    const float* a1_g  = (const float*)d_in[22];
    const float* a2_qW = (const float*)d_in[23];
    const float* a2_qb = (const float*)d_in[24];
    const float* a2_kW = (const float*)d_in[25];
    const float* a2_kb = (const float*)d_in[26];
    const float* a2_vW = (const float*)d_in[27];
    const float* a2_vb = (const float*)d_in[28];
    const float* a2_g  = (const float*)d_in[29];

    float* ws = (float*)d_ws;
    const size_t NF = (size_t)BATCH * N_PIX;  // 16384
    float* sig    = ws;                       // 16
    float* h1     = ws + 16;                  // NF*64 fl
    float* slabC  = h1 + NF * 64;             // NF*512 fl
    float* slabS1 = slabC + NF * 512;         // NF*256 fl
    float* slabS2 = slabS1 + NF * 256;        // NF*512 fl
    float* qtf    = slabS2 + NF * 512;        // NF*32 fl
    float* ktf    = qtf + NF * 32;            // NF*32 fl
    float* wspf   = ktf + NF * 32;            // ~0.6M fl

    __bf16* h1t = (__bf16*)slabS1;            // (B,N,128)
    __bf16* h2t = (__bf16*)slabS2;            // (B,N,256)
    __bf16* h3t = (__bf16*)slabS1;            // (B,N,512)
    __bf16* h5t = (__bf16*)slabS2;            // (B,N,1024)
    float*  h4t = slabC;                      // (B,N,256) fp32
    __bf16* vb1 = (__bf16*)(slabC + NF * 256);// (B,256,N)
    float*  h6t = slabC;                      // (B,N,512) fp32
    __bf16* vb2 = (__bf16*)slabS1;            // (B,512,N)
    __bf16* qt  = (__bf16*)qtf;
    __bf16* ktb = (__bf16*)ktf;
    __bf16* wsp = (__bf16*)wspf;

    __bf16* wsL2  = wsp;            // 128*128
    __bf16* wsL3  = wsL2 + 16384;   // 256*256
    __bf16* wsL4  = wsL3 + 65536;   // 512*512
    __bf16* wsA1q = wsL4 + 262144;  // 32*512
    __bf16* wsA1k = wsA1q + 16384;
    __bf16* wsA1v = wsA1k + 16384;  // 256*512
    __bf16* wsA2q = wsA1v + 131072; // 64*1024
    __bf16* wsA2k = wsA2q + 65536;
    __bf16* wsA2v = wsA2k + 65536;  // 512*1024

    dim3 blk(256);

    sigma_kernel<<<1, blk, 0, stream>>>(W1, u1, 64, 6, sig + 0);
    sigma_kernel<<<1, blk, 0, stream>>>(W2, u2, 128, 64, sig + 1);
    sigma_kernel<<<1, blk, 0, stream>>>(W3, u3, 256, 128, sig + 2);
    sigma_kernel<<<1, blk, 0, stream>>>(W4, u4, 512, 256, sig + 3);
    sigma_kernel<<<1, blk, 0, stream>>>(W5, u5, 1, 512, sig + 4);

    wsplit_kernel<<<128, blk, 0, stream>>>(W2, sig + 1, 1.f, 64, wsL2);
    wsplit_kernel<<<256, blk, 0, stream>>>(W3, sig + 2, 1.f, 128, wsL3);
    wsplit_kernel<<<512, blk, 0, stream>>>(W4, sig + 3, 1.f, 256, wsL4);
    wsplit_kernel<<<32,  blk, 0, stream>>>(a1_qW, nullptr, LOG2E, 256, wsA1q);
    wsplit_kernel<<<32,  blk, 0, stream>>>(a1_kW, nullptr, 1.f, 256, wsA1k);
    wsplit_kernel<<<256, blk, 0, stream>>>(a1_vW, nullptr, 1.f, 256, wsA1v);
    wsplit_kernel<<<64,  blk, 0, stream>>>(a2_qW, nullptr, LOG2E, 512, wsA2q);
    wsplit_kernel<<<64,  blk, 0, stream>>>(a2_kW, nullptr, 1.f, 512, wsA2k);
    wsplit_kernel<<<512, blk, 0, stream>>>(a2_vW, nullptr, 1.f, 512, wsA2v);

    // L1 (fp32) + transpose/split
    conv_f32_kernel<<<dim3(64, 1, 4), blk, 0, stream>>>(x, W1, b1, sig + 0, h1, 6, 64, 1);
    tsplit64_kernel<<<dim3(64, 4), blk, 0, stream>>>(h1, h1t);

    // L2, L3 (split-MFMA)
    mfma_conv<4, 1, 2, 0, 1><<<dim3(32, 1, 4), blk, 0, stream>>>(h1t, wsL2, b2, 1.f, h2t, 64, 128);
    mfma_conv<4, 1, 2, 0, 1><<<dim3(32, 2, 4), blk, 0, stream>>>(h2t, wsL3, b3, 1.f, h3t, 128, 256);

    // attention 1
    mfma_conv<1, 4, 4, 0, 0><<<dim3(8, 1, 4), blk, 0, stream>>>(h3t, wsA1q, a1_qb, LOG2E, qt, 256, 32);
    mfma_conv<1, 4, 4, 0, 0><<<dim3(8, 1, 4), blk, 0, stream>>>(h3t, wsA1k, a1_kb, 1.f, ktb, 256, 32);
    mfma_conv<4, 1, 1, 0, 0><<<dim3(32, 2, 4), blk, 0, stream>>>(h3t, wsA1v, a1_vb, 1.f, vb1, 256, 256);
    attn_fused3<32, 64><<<dim3(512), blk, 0, stream>>>(qt, ktb, vb1, h3t, a1_g, h4t, 256);

    // L4 (fp32-transposed input)
    mfma_conv<4, 1, 2, 1, 1><<<dim3(32, 4, 4), blk, 0, stream>>>(h4t, wsL4, b4, 1.f, h5t, 256, 512);

    // attention 2
    mfma_conv<2, 2, 4, 0, 0><<<dim3(16, 1, 4), blk, 0, stream>>>(h5t, wsA2q, a2_qb, LOG2E, qt, 512, 64);
    mfma_conv<2, 2, 4, 0, 0><<<dim3(16, 1, 4), blk, 0, stream>>>(h5t, wsA2k, a2_kb, 1.f, ktb, 512, 64);
    mfma_conv<4, 1, 1, 0, 0><<<dim3(32, 4, 4), blk, 0, stream>>>(h5t, wsA2v, a2_vb, 1.f, vb2, 512, 512);
    attn_fused3<64, 128><<<dim3(512), blk, 0, stream>>>(qt, ktb, vb2, h5t, a2_g, h6t, 512);

    // L5
    l5_kernel<<<4096, blk, 0, stream>>>(h6t, W5, b5, sig + 4, (float*)d_out);
}